// Round 1
// 299.417 us; speedup vs baseline: 1.0719x; 1.0719x over previous
//
#include <hip/hip_runtime.h>
#include <hip/hip_bf16.h>
#include <stdint.h>

typedef __attribute__((ext_vector_type(8))) short short8;
typedef __attribute__((ext_vector_type(4))) float floatx4;
typedef __attribute__((ext_vector_type(8))) int int8v;
typedef __attribute__((ext_vector_type(4))) int int4v;

__device__ __forceinline__ ushort f2b(float f) {
    union { float f; uint32_t u; } v; v.f = f;
    uint32_t r = (v.u + 0x7fffu + ((v.u >> 16) & 1u)) >> 16;
    return (ushort)r;
}
__device__ __forceinline__ float b2f(ushort b) {
    union { uint32_t u; float f; } v; v.u = ((uint32_t)b) << 16;
    return v.f;
}
__device__ __forceinline__ uint8_t f2fp8(float f) {
    return (uint8_t)(__builtin_amdgcn_cvt_pk_fp8_f32(f, f, 0, false) & 0xff);
}

__device__ __forceinline__ void gl_lds16(const void* g, void* l) {
    __builtin_amdgcn_global_load_lds(
        (const __attribute__((address_space(1))) void*)g,
        (__attribute__((address_space(3))) void*)l, 16, 0, 0);
}

// ---------------- elementwise f32 -> fp8 e4m3 (*s), float4 in, 4 bytes out ----------
__global__ __launch_bounds__(256) void convert_f32_fp8(const float* __restrict__ in,
                                                       uint8_t* __restrict__ out,
                                                       int n4, float s) {
    int i = blockIdx.x * 256 + threadIdx.x;
    if (i < n4) {
        float4 v = ((const float4*)in)[i];
        int p = __builtin_amdgcn_cvt_pk_fp8_f32(v.x * s, v.y * s, 0, false);
        p = __builtin_amdgcn_cvt_pk_fp8_f32(v.z * s, v.w * s, p, true);
        ((uint32_t*)out)[i] = p;
    }
}

// ---------------- elementwise f32 -> bf16, float4 in, ushort4 out ----------------
__global__ __launch_bounds__(256) void convert_f32_bf16(const float* __restrict__ in,
                                                        ushort* __restrict__ out, int n4) {
    int i = blockIdx.x * 256 + threadIdx.x;
    if (i < n4) {
        float4 v = ((const float4*)in)[i];
        ushort4 o;
        o.x = f2b(v.x); o.y = f2b(v.y); o.z = f2b(v.z); o.w = f2b(v.w);
        ((ushort4*)out)[i] = o;
    }
}

// ---------------- transpose bf16[R,C] -> fp8[C,R] (*s) ----------------
__global__ __launch_bounds__(256) void transpose_bf16_to_fp8(const ushort* __restrict__ in,
                                                             uint8_t* __restrict__ out,
                                                             int R, int Cc, float s) {
    __shared__ uint8_t t[32][36];
    int bx = blockIdx.x * 32, by = blockIdx.y * 32;
    int tx = threadIdx.x & 31, ty = threadIdx.x >> 5;
    #pragma unroll
    for (int i = 0; i < 32; i += 8)
        t[ty + i][tx] = f2fp8(b2f(in[(size_t)(by + ty + i) * Cc + bx + tx]) * s);
    __syncthreads();
    #pragma unroll
    for (int i = 0; i < 32; i += 8)
        out[(size_t)(bx + ty + i) * R + by + tx] = t[tx][ty + i];
}

// ---------------- transpose f32[R,C] -> bf16[C,R] (for WkT) -----
__global__ __launch_bounds__(256) void transpose_f32_to_bf16(const float* __restrict__ in,
                                                             ushort* __restrict__ out,
                                                             int R, int Cc) {
    __shared__ ushort t[32][33];
    int bx = blockIdx.x * 32, by = blockIdx.y * 32;
    int tx = threadIdx.x & 31, ty = threadIdx.x >> 5;
    #pragma unroll
    for (int i = 0; i < 32; i += 8)
        t[ty + i][tx] = f2b(in[(size_t)(by + ty + i) * Cc + bx + tx]);
    __syncthreads();
    #pragma unroll
    for (int i = 0; i < 32; i += 8)
        out[(size_t)(bx + ty + i) * R + by + tx] = t[tx][ty + i];
}

// ---------------- row L2-normalize f32 in -> bf16 out ----------------
__global__ __launch_bounds__(256) void normalize_f32_to_bf16(const float* __restrict__ in,
                                                             ushort* __restrict__ out, int D) {
    int row = blockIdx.x;
    const float* x = in + (size_t)row * D;
    float s = 0.0f;
    for (int i = threadIdx.x; i < D; i += 256) { float t = x[i]; s += t * t; }
    __shared__ float sm[4];
    #pragma unroll
    for (int off = 32; off; off >>= 1) s += __shfl_down(s, off, 64);
    if ((threadIdx.x & 63) == 0) sm[threadIdx.x >> 6] = s;
    __syncthreads();
    float inv = 1.0f / sqrtf(sm[0] + sm[1] + sm[2] + sm[3]);
    ushort* o = out + (size_t)row * D;
    for (int i = threadIdx.x; i < D; i += 256) o[i] = f2b(x[i] * inv);
}

// =============== MX-fp8 MFMA GEMM: C = scale*(A @ B^T) [+bias][*rsqrt(rn)] ==========
// 128x128 tile, BK=128. fp8 e4m3 operands, MX scales fixed at 1.0 (0x7f).
// 16-B-chunk XOR swizzle on K segments (2-way conflict = free).
template<typename OutT, bool NGUARD, bool SUMSQ, bool ROWSCALE, bool STORE>
__global__ __launch_bounds__(256, 3) void gemm_f8(
    const uint8_t* __restrict__ A, const uint8_t* __restrict__ B,
    const float* __restrict__ bias, float* __restrict__ rn, OutT* __restrict__ C,
    int M, int N, int K, int Nld, float scale)
{
    __shared__ alignas(16) uint8_t As[128 * 128];
    __shared__ alignas(16) uint8_t Bs[128 * 128];
    const int id = threadIdx.x;
    const int wave = id >> 6, lane = id & 63;

    // XCD-aware swizzle: all col-blocks of one row-panel -> same XCD
    int bxi = blockIdx.x, byi = blockIdx.y;
    if ((gridDim.y & 7) == 0) {
        int i = byi * gridDim.x + bxi;
        int xcd = i & 7;
        int j = i >> 3;
        bxi = j % gridDim.x;
        byi = xcd + 8 * (j / gridDim.x);
    }
    const int row0 = byi * 128, col0 = bxi * 128;
    const int wm = (wave >> 1) * 64, wn = (wave & 1) * 64;

    const int fr = id >> 3;
    const int fss = (id & 7) ^ (fr & 7);
    const uint8_t* Agp[4];
    const uint8_t* Bgp[4];
    #pragma unroll
    for (int t = 0; t < 4; t++) {
        int ar = row0 + fr + 32 * t;
        int br = col0 + fr + 32 * t;
        if (NGUARD) br = min(br, N - 1);
        Agp[t] = A + (size_t)ar * K + fss * 16;
        Bgp[t] = B + (size_t)br * K + fss * 16;
    }

    floatx4 acc[4][4] = {};
    const int mrow = lane & 15;
    const int g2 = (lane >> 4) * 2;

    for (int k0 = 0; k0 < K; k0 += 128) {
        #pragma unroll
        for (int t = 0; t < 4; t++) {
            gl_lds16(Agp[t] + k0, &As[id * 16 + 4096 * t]);
            gl_lds16(Bgp[t] + k0, &Bs[id * 16 + 4096 * t]);
        }
        __syncthreads();
        int8v a[4], b[4];
        #pragma unroll
        for (int i = 0; i < 4; i++) {
            int r = wm + i * 16 + mrow, rs = r & 7;
            int4v lo = *(const int4v*)&As[r * 128 + ((g2    ) ^ rs) * 16];
            int4v hi = *(const int4v*)&As[r * 128 + ((g2 + 1) ^ rs) * 16];
            a[i] = __builtin_shufflevector(lo, hi, 0, 1, 2, 3, 4, 5, 6, 7);
        }
        #pragma unroll
        for (int j = 0; j < 4; j++) {
            int r = wn + j * 16 + mrow, rs = r & 7;
            int4v lo = *(const int4v*)&Bs[r * 128 + ((g2    ) ^ rs) * 16];
            int4v hi = *(const int4v*)&Bs[r * 128 + ((g2 + 1) ^ rs) * 16];
            b[j] = __builtin_shufflevector(lo, hi, 0, 1, 2, 3, 4, 5, 6, 7);
        }
        #pragma unroll
        for (int i = 0; i < 4; i++)
            #pragma unroll
            for (int j = 0; j < 4; j++)
                acc[i][j] = __builtin_amdgcn_mfma_scale_f32_16x16x128_f8f6f4(
                    a[i], b[j], acc[i][j], 0, 0, 0, 0x7f7f7f7f, 0, 0x7f7f7f7f);
        __syncthreads();
    }

    // C/D layout: col = lane&15, row = (lane>>4)*4 + r
    const int ccol0 = col0 + wn + (lane & 15);
    const int crow0 = row0 + wm + (lane >> 4) * 4;
    float bv[4];
    #pragma unroll
    for (int j = 0; j < 4; j++) {
        int col = ccol0 + j * 16;
        bv[j] = (bias && (!NGUARD || col < N)) ? bias[col] : 0.0f;
    }
    #pragma unroll
    for (int i = 0; i < 4; i++) {
        #pragma unroll
        for (int r = 0; r < 4; r++) {
            const int row = crow0 + i * 16 + r;
            float inv = 1.0f;
            if constexpr (ROWSCALE) inv = rsqrtf(rn[row]);
            float ss = 0.0f;
            #pragma unroll
            for (int j = 0; j < 4; j++) {
                int col = ccol0 + j * 16;
                float v = acc[i][j][r] * scale * inv + bv[j];
                if constexpr (SUMSQ) ss += v * v;
                if constexpr (STORE) {
                    if (!NGUARD || col < N) {
                        if constexpr (sizeof(OutT) == 1)      C[(size_t)row * Nld + col] = (OutT)f2fp8(v);
                        else if constexpr (sizeof(OutT) == 2) C[(size_t)row * Nld + col] = (OutT)f2b(v);
                        else                                   C[(size_t)row * Nld + col] = v;
                    }
                }
            }
            if constexpr (SUMSQ) {
                #pragma unroll
                for (int m = 1; m < 16; m <<= 1) ss += __shfl_xor(ss, m, 64);
                if ((lane & 15) == 0) atomicAdd(&rn[row], ss);
            }
        }
    }
}

// =============== generic small bf16 MFMA GEMM: C = scale*(A @ B^T) ==========
// 64x64 tile, BK=128, 4 waves (each 32x32). A[M,K], B[N,K] bf16 row-major.
// Same 16B-chunk XOR swizzle (16 chunks/row of 256B); gl_lds width-16 staging.
template<typename OutT, bool MGUARD>
__global__ __launch_bounds__(256) void gemm_bf16_64(
    const ushort* __restrict__ A, const ushort* __restrict__ B,
    OutT* __restrict__ Cc, int M, int N, int K, int Nld, float scale)
{
    __shared__ alignas(16) uint8_t As[64 * 256];
    __shared__ alignas(16) uint8_t Bs[64 * 256];
    const int id = threadIdx.x;
    const int wave = id >> 6, lane = id & 63;
    const int row0 = blockIdx.y * 64, col0 = blockIdx.x * 64;
    const int wm = (wave >> 1) * 32, wn = (wave & 1) * 32;

    // staging: f = id + 256t -> row = f>>4, dest chunk = f&15 (16 x 16B chunks per row)
    // source chunk = dest ^ (row&7); (row&7) is t-invariant since 16t == 0 mod 8... (16t mod 8 == 0)
    const int fr = id >> 4;
    const int sch = (id & 15) ^ (fr & 7);
    const uint8_t* Ab = (const uint8_t*)A;
    const uint8_t* Bb = (const uint8_t*)B;
    const uint8_t* Agp[4];
    const uint8_t* Bgp[4];
    #pragma unroll
    for (int t = 0; t < 4; t++) {
        int ar = row0 + fr + 16 * t;
        if (MGUARD) ar = min(ar, M - 1);
        int br = col0 + fr + 16 * t;
        Agp[t] = Ab + (size_t)ar * (K * 2) + sch * 16;
        Bgp[t] = Bb + (size_t)br * (K * 2) + sch * 16;
    }

    floatx4 acc[2][2] = {};
    const int mrow = lane & 15, g = lane >> 4;

    for (int k0 = 0; k0 < K; k0 += 128) {
        #pragma unroll
        for (int t = 0; t < 4; t++) {
            gl_lds16(Agp[t] + k0 * 2, &As[id * 16 + 4096 * t]);
            gl_lds16(Bgp[t] + k0 * 2, &Bs[id * 16 + 4096 * t]);
        }
        __syncthreads();
        #pragma unroll
        for (int ks = 0; ks < 4; ks++) {
            short8 a[2], b[2];
            #pragma unroll
            for (int i = 0; i < 2; i++) {
                int r = wm + i * 16 + mrow;
                a[i] = *(const short8*)&As[r * 256 + ((ks * 4 + g) ^ (r & 7)) * 16];
            }
            #pragma unroll
            for (int j = 0; j < 2; j++) {
                int r = wn + j * 16 + mrow;
                b[j] = *(const short8*)&Bs[r * 256 + ((ks * 4 + g) ^ (r & 7)) * 16];
            }
            #pragma unroll
            for (int i = 0; i < 2; i++)
                #pragma unroll
                for (int j = 0; j < 2; j++)
                    acc[i][j] = __builtin_amdgcn_mfma_f32_16x16x32_bf16(a[i], b[j], acc[i][j], 0, 0, 0);
        }
        __syncthreads();
    }

    const int ccol0 = col0 + wn + (lane & 15);
    const int crow0 = row0 + wm + (lane >> 4) * 4;
    #pragma unroll
    for (int i = 0; i < 2; i++) {
        #pragma unroll
        for (int r = 0; r < 4; r++) {
            const int row = crow0 + i * 16 + r;
            if (MGUARD && row >= M) continue;
            #pragma unroll
            for (int j = 0; j < 2; j++) {
                int col = ccol0 + j * 16;
                float v = acc[i][j][r] * scale;
                if constexpr (sizeof(OutT) == 1)      Cc[(size_t)row * Nld + col] = (OutT)f2fp8(v);
                else if constexpr (sizeof(OutT) == 2) Cc[(size_t)row * Nld + col] = (OutT)f2b(v);
                else                                   Cc[(size_t)row * Nld + col] = v;
            }
        }
    }
}

// --------- sparsemax rows of 512, in-place f32 + fp8(x32) copy; 1 wave per row ------
__global__ __launch_bounds__(256) void sparsemax_k(float* __restrict__ S,
                                                   uint8_t* __restrict__ A8) {
    int wave = threadIdx.x >> 6, lane = threadIdx.x & 63;
    int row = blockIdx.x * 4 + wave;
    float* z = S + (size_t)row * 512;
    float v[8];
    #pragma unroll
    for (int j = 0; j < 8; j++) v[j] = z[lane + 64 * j];
    float mx = v[0];
    #pragma unroll
    for (int j = 1; j < 8; j++) mx = fmaxf(mx, v[j]);
    #pragma unroll
    for (int off = 1; off < 64; off <<= 1) mx = fmaxf(mx, __shfl_xor(mx, off, 64));
    float lo = mx - 1.0f, hi = mx;
    for (int it = 0; it < 30; it++) {
        float tau = 0.5f * (lo + hi);
        float s = 0.0f;
        #pragma unroll
        for (int j = 0; j < 8; j++) s += fmaxf(v[j] - tau, 0.0f);
        #pragma unroll
        for (int off = 1; off < 64; off <<= 1) s += __shfl_xor(s, off, 64);
        if (s >= 1.0f) lo = tau; else hi = tau;
    }
    float tau = 0.5f * (lo + hi);
    uint8_t* o8 = A8 + (size_t)row * 512;
    #pragma unroll
    for (int j = 0; j < 8; j++) {
        float o = fmaxf(v[j] - tau, 0.0f);
        z[lane + 64 * j] = o;
        o8[lane + 64 * j] = f2fp8(o * 32.0f);
    }
}

extern "C" void kernel_launch(void* const* d_in, const int* in_sizes, int n_in,
                              void* d_out, int out_size, void* d_ws, size_t ws_size,
                              hipStream_t stream) {
    const float* x        = (const float*)d_in[0];   // [16384,1024]
    const float* concepts = (const float*)d_in[1];   // [512,1024]
    const float* Wq       = (const float*)d_in[2];   // [1024,1024]
    const float* Wk       = (const float*)d_in[3];   // [1024,1024]
    const float* fc_w     = (const float*)d_in[4];   // [1000,1024]
    const float* fc_b     = (const float*)d_in[5];   // [1000]

    const int B = 16384, D = 1024, C = 512, N = 1000;

    float* out  = (float*)d_out;                       // [B,N]
    float* attn = out + (size_t)B * N;                 // [B,C]
    float* sim  = attn + (size_t)B * C;                // [C,C]

    // ---- ws layout (~34 MiB) ----
    uint8_t* w = (uint8_t*)d_ws;
    uint8_t* x_f8    = w;                              // [B,D]   16 MiB
    uint8_t* attn_f8 = w + (16ull << 20);              // [B,C]    8 MiB
    ushort*  Wq_bf   = (ushort*)(w + (24ull << 20));   // [D,D]    2 MiB
    ushort*  fcw_bf  = (ushort*)(w + (26ull << 20));   // [N,D]    2 MiB
    ushort*  WkT     = (ushort*)(w + (28ull << 20));   // [D,D]    2 MiB
    ushort*  c_bf    = (ushort*)(w + (30ull << 20));   // [C,D]    1 MiB
    ushort*  kmat_bf = (ushort*)(w + (31ull << 20));   // [C,D]    1 MiB
    uint8_t* cT_f8   = w + (32ull << 20);              // [D,C]  0.5 MiB
    uint8_t* W2T_f8  = w + (32ull << 20) + (512ull << 10); // [C,D] 0.5 MiB
    uint8_t* W3T_f8  = w + (33ull << 20);              // [N,C]  0.5 MiB
    float*   rn      = (float*)(w + (34ull << 20));    // [B]    64 KiB

    // Reassociation: scores = x @ (Wq @ kmat^T) = x @ W2  (W2T = kmat @ Wq^T)
    //                out    = (attn @ (c @ fcw^T)) * rsqrt(|attn@c|^2) + b  (W3T = fcw @ c^T)
    // scale bookkeeping (powers of 2, folded into GEMM output scales):
    //   x *1, W2T *16   -> scores scale (1/32)/16 = 1/512 (f32 out)
    //   attn *32, c *16 -> rn GEMM scale 1/512 (true summary; sumsq only, no store)
    //   attn *32, W3T *16 -> out scale 1/512, * rsqrt(rn), + bias

    // independent prep
    convert_f32_fp8<<<B * D / 4 / 256, 256, 0, stream>>>(x, x_f8, B * D / 4, 1.0f);
    normalize_f32_to_bf16<<<C, 256, 0, stream>>>(concepts, c_bf, D);
    transpose_f32_to_bf16<<<dim3(D / 32, D / 32), 256, 0, stream>>>(Wk, WkT, D, D);
    convert_f32_bf16<<<D * D / 4 / 256, 256, 0, stream>>>(Wq, Wq_bf, D * D / 4);
    convert_f32_bf16<<<(N * D / 4 + 255) / 256, 256, 0, stream>>>(fc_w, fcw_bf, N * D / 4);
    transpose_bf16_to_fp8<<<dim3(D / 32, C / 32), 256, 0, stream>>>(c_bf, cT_f8, C, D, 16.0f);
    // small weight-side GEMMs (bf16 MFMA, 64^2 tiles)
    gemm_bf16_64<ushort, false><<<dim3(D / 64, C / 64), 256, 0, stream>>>(
        c_bf, WkT, kmat_bf, C, D, D, D, 1.0f);                         // kmat = c @ Wk
    gemm_bf16_64<float, false><<<dim3(C / 64, C / 64), 256, 0, stream>>>(
        c_bf, c_bf, sim, C, C, D, C, 1.0f);                            // sim = c @ c^T
    gemm_bf16_64<uint8_t, false><<<dim3(D / 64, C / 64), 256, 0, stream>>>(
        kmat_bf, Wq_bf, W2T_f8, C, D, D, D, 16.0f);                    // W2T = kmat @ Wq^T
    gemm_bf16_64<uint8_t, true><<<dim3(C / 64, (N + 63) / 64), 256, 0, stream>>>(
        fcw_bf, c_bf, W3T_f8, N, C, D, C, 16.0f);                      // W3T = fcw @ c^T
    // scores = (x @ W2)/32 -> attn slot of d_out (f32)
    gemm_f8<float, false, false, false, true><<<dim3(C / 128, B / 128), 256, 0, stream>>>(
        x_f8, W2T_f8, nullptr, nullptr, attn, B, C, D, C, 1.0f / 512.0f);
    // sparsemax in place + fp8(*32) copy
    sparsemax_k<<<B / 4, 256, 0, stream>>>(attn, attn_f8);
    // rn = rowwise |attn @ c|^2 (sumsq only, no store)
    hipMemsetAsync(rn, 0, B * sizeof(float), stream);
    gemm_f8<uint8_t, false, true, false, false><<<dim3(D / 128, B / 128), 256, 0, stream>>>(
        attn_f8, cT_f8, nullptr, rn, nullptr, B, D, C, D, 1.0f / 512.0f);
    // out = (attn @ W3) * rsqrt(rn) + fc_b
    gemm_f8<float, true, false, true, true><<<dim3((N + 127) / 128, B / 128), 256, 0, stream>>>(
        attn_f8, W3T_f8, fc_b, rn, out, B, N, C, N, 1.0f / 512.0f);
}

// Round 3
// 272.662 us; speedup vs baseline: 1.1771x; 1.0981x over previous
//
#include <hip/hip_runtime.h>
#include <hip/hip_bf16.h>
#include <stdint.h>

typedef __attribute__((ext_vector_type(8))) short short8;
typedef __attribute__((ext_vector_type(4))) float floatx4;
typedef __attribute__((ext_vector_type(8))) int int8v;
typedef __attribute__((ext_vector_type(4))) int int4v;

__device__ __forceinline__ ushort f2b(float f) {
    union { float f; uint32_t u; } v; v.f = f;
    uint32_t r = (v.u + 0x7fffu + ((v.u >> 16) & 1u)) >> 16;
    return (ushort)r;
}
__device__ __forceinline__ float b2f(ushort b) {
    union { uint32_t u; float f; } v; v.u = ((uint32_t)b) << 16;
    return v.f;
}
__device__ __forceinline__ uint8_t f2fp8(float f) {
    return (uint8_t)(__builtin_amdgcn_cvt_pk_fp8_f32(f, f, 0, false) & 0xff);
}

__device__ __forceinline__ void gl_lds16(const void* g, void* l) {
    __builtin_amdgcn_global_load_lds(
        (const __attribute__((address_space(1))) void*)g,
        (__attribute__((address_space(3))) void*)l, 16, 0, 0);
}

// ================= prep mega-kernel: all elementwise/transpose prep in ONE launch ====
// block ranges:
//   [0,16384)        : x f32 -> fp8            (16M elems, 1024/block)
//   [16384,17408)    : Wq f32 -> bf16
//   [17408,18432)    : Wk f32 -> bf16
//   [18432,19432)    : fc_w f32 -> bf16
//   [19432,19944)    : concepts row b: L2-normalize -> c_bf (one row/block)
//   [19944,19960)    : cT_f8 transpose blocks (32 rows x 1024 cols each, inline norms)
__global__ __launch_bounds__(256) void prep_all(
    const float* __restrict__ x, const float* __restrict__ Wq,
    const float* __restrict__ Wk, const float* __restrict__ fcw,
    const float* __restrict__ concepts,
    uint8_t* __restrict__ x_f8, ushort* __restrict__ Wq_bf,
    ushort* __restrict__ Wk_bf, ushort* __restrict__ fcw_bf,
    ushort* __restrict__ c_bf, uint8_t* __restrict__ cT_f8)
{
    __shared__ float smem_f[8];
    __shared__ float partial[32][8];
    __shared__ float invn[32];
    __shared__ uint8_t tile8[32 * 1044];   // stride 1044: 4B-aligned; 1044/4=261 odd mod 32 -> conflict-free column reads

    int b = blockIdx.x;
    const int tid = threadIdx.x;

    if (b < 16384) {                       // x -> fp8
        int i = b * 256 + tid;
        float4 v = ((const float4*)x)[i];
        int p = __builtin_amdgcn_cvt_pk_fp8_f32(v.x, v.y, 0, false);
        p = __builtin_amdgcn_cvt_pk_fp8_f32(v.z, v.w, p, true);
        ((uint32_t*)x_f8)[i] = p;
        return;
    }
    b -= 16384;
    if (b < 1024) {                        // Wq -> bf16
        int i = b * 256 + tid;
        float4 v = ((const float4*)Wq)[i];
        ushort4 o; o.x = f2b(v.x); o.y = f2b(v.y); o.z = f2b(v.z); o.w = f2b(v.w);
        ((ushort4*)Wq_bf)[i] = o;
        return;
    }
    b -= 1024;
    if (b < 1024) {                        // Wk -> bf16
        int i = b * 256 + tid;
        float4 v = ((const float4*)Wk)[i];
        ushort4 o; o.x = f2b(v.x); o.y = f2b(v.y); o.z = f2b(v.z); o.w = f2b(v.w);
        ((ushort4*)Wk_bf)[i] = o;
        return;
    }
    b -= 1024;
    if (b < 1000) {                        // fc_w -> bf16
        int i = b * 256 + tid;
        float4 v = ((const float4*)fcw)[i];
        ushort4 o; o.x = f2b(v.x); o.y = f2b(v.y); o.z = f2b(v.z); o.w = f2b(v.w);
        ((ushort4*)fcw_bf)[i] = o;
        return;
    }
    b -= 1000;
    if (b < 512) {                         // concept row L2-normalize -> bf16
        const float* xr = concepts + (size_t)b * 1024;
        float vv[4]; float s = 0.0f;
        #pragma unroll
        for (int j = 0; j < 4; j++) { vv[j] = xr[tid + 256 * j]; s += vv[j] * vv[j]; }
        #pragma unroll
        for (int off = 32; off; off >>= 1) s += __shfl_down(s, off, 64);
        if ((tid & 63) == 0) smem_f[tid >> 6] = s;
        __syncthreads();
        float inv = rsqrtf(smem_f[0] + smem_f[1] + smem_f[2] + smem_f[3]);
        ushort* o = c_bf + (size_t)b * 1024;
        #pragma unroll
        for (int j = 0; j < 4; j++) o[tid + 256 * j] = f2b(vv[j] * inv);
        return;
    }
    b -= 512;
    {                                      // cT_f8: rows r0..r0+31, all 1024 cols
        const int r0 = b * 32;
        // phase 1: row norms (8 threads/row)
        {
            int row = tid >> 3, sub = tid & 7;
            const float* rp = concepts + (size_t)(r0 + row) * 1024 + sub * 128;
            float s = 0.0f;
            #pragma unroll
            for (int j = 0; j < 32; j++) {
                float4 v = ((const float4*)rp)[j];
                s += v.x * v.x + v.y * v.y + v.z * v.z + v.w * v.w;
            }
            partial[row][sub] = s;
        }
        __syncthreads();
        if (tid < 32) {
            float t = 0.0f;
            #pragma unroll
            for (int j = 0; j < 8; j++) t += partial[tid][j];
            invn[tid] = rsqrtf(t);
        }
        __syncthreads();
        // phase 2: coalesced read, fp8(*16) pack into LDS tile
        for (int idx = tid; idx < 32 * 256; idx += 256) {
            int row = idx >> 8, d4 = idx & 255;
            float4 v = ((const float4*)(concepts + (size_t)(r0 + row) * 1024))[d4];
            float sc = invn[row] * 16.0f;
            int p = __builtin_amdgcn_cvt_pk_fp8_f32(v.x * sc, v.y * sc, 0, false);
            p = __builtin_amdgcn_cvt_pk_fp8_f32(v.z * sc, v.w * sc, p, true);
            *(uint32_t*)&tile8[row * 1044 + d4 * 4] = p;
        }
        __syncthreads();
        // phase 3: transposed write, coalesced over rows
        for (int idx = tid; idx < 32 * 1024; idx += 256) {
            int d = idx >> 5, row = idx & 31;
            cT_f8[(size_t)d * 512 + r0 + row] = tile8[row * 1044 + d];
        }
    }
}

// =============== MX-fp8 MFMA GEMM: C = scale*(A @ B^T) [+bias][*rsqrt(rn)] ==========
template<typename OutT, bool NGUARD, bool SUMSQ, bool ROWSCALE, bool STORE>
__global__ __launch_bounds__(256, 3) void gemm_f8(
    const uint8_t* __restrict__ A, const uint8_t* __restrict__ B,
    const float* __restrict__ bias, float* __restrict__ rn, OutT* __restrict__ C,
    int M, int N, int K, int Nld, float scale)
{
    __shared__ alignas(16) uint8_t As[128 * 128];
    __shared__ alignas(16) uint8_t Bs[128 * 128];
    const int id = threadIdx.x;
    const int wave = id >> 6, lane = id & 63;

    int bxi = blockIdx.x, byi = blockIdx.y;
    if ((gridDim.y & 7) == 0) {
        int i = byi * gridDim.x + bxi;
        int xcd = i & 7;
        int j = i >> 3;
        bxi = j % gridDim.x;
        byi = xcd + 8 * (j / gridDim.x);
    }
    const int row0 = byi * 128, col0 = bxi * 128;
    const int wm = (wave >> 1) * 64, wn = (wave & 1) * 64;

    const int fr = id >> 3;
    const int fss = (id & 7) ^ (fr & 7);
    const uint8_t* Agp[4];
    const uint8_t* Bgp[4];
    #pragma unroll
    for (int t = 0; t < 4; t++) {
        int ar = row0 + fr + 32 * t;
        int br = col0 + fr + 32 * t;
        if (NGUARD) br = min(br, N - 1);
        Agp[t] = A + (size_t)ar * K + fss * 16;
        Bgp[t] = B + (size_t)br * K + fss * 16;
    }

    floatx4 acc[4][4] = {};
    const int mrow = lane & 15;
    const int g2 = (lane >> 4) * 2;

    for (int k0 = 0; k0 < K; k0 += 128) {
        #pragma unroll
        for (int t = 0; t < 4; t++) {
            gl_lds16(Agp[t] + k0, &As[id * 16 + 4096 * t]);
            gl_lds16(Bgp[t] + k0, &Bs[id * 16 + 4096 * t]);
        }
        __syncthreads();
        int8v a[4], b[4];
        #pragma unroll
        for (int i = 0; i < 4; i++) {
            int r = wm + i * 16 + mrow, rs = r & 7;
            int4v lo = *(const int4v*)&As[r * 128 + ((g2    ) ^ rs) * 16];
            int4v hi = *(const int4v*)&As[r * 128 + ((g2 + 1) ^ rs) * 16];
            a[i] = __builtin_shufflevector(lo, hi, 0, 1, 2, 3, 4, 5, 6, 7);
        }
        #pragma unroll
        for (int j = 0; j < 4; j++) {
            int r = wn + j * 16 + mrow, rs = r & 7;
            int4v lo = *(const int4v*)&Bs[r * 128 + ((g2    ) ^ rs) * 16];
            int4v hi = *(const int4v*)&Bs[r * 128 + ((g2 + 1) ^ rs) * 16];
            b[j] = __builtin_shufflevector(lo, hi, 0, 1, 2, 3, 4, 5, 6, 7);
        }
        #pragma unroll
        for (int i = 0; i < 4; i++)
            #pragma unroll
            for (int j = 0; j < 4; j++)
                acc[i][j] = __builtin_amdgcn_mfma_scale_f32_16x16x128_f8f6f4(
                    a[i], b[j], acc[i][j], 0, 0, 0, 0x7f7f7f7f, 0, 0x7f7f7f7f);
        __syncthreads();
    }

    const int ccol0 = col0 + wn + (lane & 15);
    const int crow0 = row0 + wm + (lane >> 4) * 4;
    float bv[4];
    #pragma unroll
    for (int j = 0; j < 4; j++) {
        int col = ccol0 + j * 16;
        bv[j] = (bias && (!NGUARD || col < N)) ? bias[col] : 0.0f;
    }
    #pragma unroll
    for (int i = 0; i < 4; i++) {
        #pragma unroll
        for (int r = 0; r < 4; r++) {
            const int row = crow0 + i * 16 + r;
            float inv = 1.0f;
            if constexpr (ROWSCALE) inv = rsqrtf(rn[row]);
            float ss = 0.0f;
            #pragma unroll
            for (int j = 0; j < 4; j++) {
                int col = ccol0 + j * 16;
                float v = acc[i][j][r] * scale * inv + bv[j];
                if constexpr (SUMSQ) ss += v * v;
                if constexpr (STORE) {
                    if (!NGUARD || col < N) {
                        if constexpr (sizeof(OutT) == 1)      C[(size_t)row * Nld + col] = (OutT)f2fp8(v);
                        else if constexpr (sizeof(OutT) == 2) C[(size_t)row * Nld + col] = (OutT)f2b(v);
                        else                                   C[(size_t)row * Nld + col] = v;
                    }
                }
            }
            if constexpr (SUMSQ) {
                #pragma unroll
                for (int m = 1; m < 16; m <<= 1) ss += __shfl_xor(ss, m, 64);
                if ((lane & 15) == 0) atomicAdd(&rn[row], ss);
            }
        }
    }
}

// =============== shared 64x64 bf16 GEMM body: C = scale*(A @ B^T) ==========
// outmode: 0 = f32, 1 = fp8, 2 = bf16
__device__ __forceinline__ void gemm64_body(
    uint8_t* As, uint8_t* Bs,
    const ushort* __restrict__ A, const ushort* __restrict__ B, void* Cout, int outmode,
    int M, int N, int K, int Nld, float scale, int bx, int by, bool mguard)
{
    const int id = threadIdx.x;
    const int wave = id >> 6, lane = id & 63;
    const int row0 = by * 64, col0 = bx * 64;
    const int wm = (wave >> 1) * 32, wn = (wave & 1) * 32;

    const int fr = id >> 4;
    const int sch = (id & 15) ^ (fr & 7);
    const uint8_t* Ab = (const uint8_t*)A;
    const uint8_t* Bb = (const uint8_t*)B;
    const uint8_t* Agp[4];
    const uint8_t* Bgp[4];
    #pragma unroll
    for (int t = 0; t < 4; t++) {
        int ar = row0 + fr + 16 * t;
        if (mguard) ar = min(ar, M - 1);
        int br = col0 + fr + 16 * t;
        Agp[t] = Ab + (size_t)ar * (K * 2) + sch * 16;
        Bgp[t] = Bb + (size_t)br * (K * 2) + sch * 16;
    }

    floatx4 acc[2][2] = {};
    const int mrow = lane & 15, g = lane >> 4;

    for (int k0 = 0; k0 < K; k0 += 128) {
        #pragma unroll
        for (int t = 0; t < 4; t++) {
            gl_lds16(Agp[t] + (size_t)k0 * 2, &As[id * 16 + 4096 * t]);
            gl_lds16(Bgp[t] + (size_t)k0 * 2, &Bs[id * 16 + 4096 * t]);
        }
        __syncthreads();
        #pragma unroll
        for (int ks = 0; ks < 4; ks++) {
            short8 a[2], b[2];
            #pragma unroll
            for (int i = 0; i < 2; i++) {
                int r = wm + i * 16 + mrow;
                a[i] = *(const short8*)&As[r * 256 + ((ks * 4 + g) ^ (r & 7)) * 16];
            }
            #pragma unroll
            for (int j = 0; j < 2; j++) {
                int r = wn + j * 16 + mrow;
                b[j] = *(const short8*)&Bs[r * 256 + ((ks * 4 + g) ^ (r & 7)) * 16];
            }
            #pragma unroll
            for (int i = 0; i < 2; i++)
                #pragma unroll
                for (int j = 0; j < 2; j++)
                    acc[i][j] = __builtin_amdgcn_mfma_f32_16x16x32_bf16(a[i], b[j], acc[i][j], 0, 0, 0);
        }
        __syncthreads();
    }

    const int ccol0 = col0 + wn + (lane & 15);
    const int crow0 = row0 + wm + (lane >> 4) * 4;
    #pragma unroll
    for (int i = 0; i < 2; i++) {
        #pragma unroll
        for (int r = 0; r < 4; r++) {
            const int row = crow0 + i * 16 + r;
            if (mguard && row >= M) continue;
            #pragma unroll
            for (int j = 0; j < 2; j++) {
                int col = ccol0 + j * 16;
                float v = acc[i][j][r] * scale;
                if (outmode == 0)      ((float*)Cout)[(size_t)row * Nld + col] = v;
                else if (outmode == 1) ((uint8_t*)Cout)[(size_t)row * Nld + col] = f2fp8(v);
                else                   ((ushort*)Cout)[(size_t)row * Nld + col] = f2b(v);
            }
        }
    }
}

// P2 = Wq @ Wk^T   [1024,1024] bf16
__global__ __launch_bounds__(256) void gemm_p2(const ushort* __restrict__ Wq_bf,
                                               const ushort* __restrict__ Wk_bf,
                                               ushort* __restrict__ P2) {
    __shared__ alignas(16) uint8_t As[64 * 256];
    __shared__ alignas(16) uint8_t Bs[64 * 256];
    gemm64_body(As, Bs, Wq_bf, Wk_bf, P2, 2, 1024, 1024, 1024, 1024, 1.0f,
                blockIdx.x, blockIdx.y, false);
}

// batched: sim = c@c^T (f32) | W3T = fcw@c^T (fp8*16) | W2T = c@P2^T (fp8*16)
__global__ __launch_bounds__(256) void gemm_batch3(
    const ushort* __restrict__ c_bf, const ushort* __restrict__ fcw_bf,
    const ushort* __restrict__ P2,
    float* __restrict__ sim, uint8_t* __restrict__ W3T, uint8_t* __restrict__ W2T)
{
    __shared__ alignas(16) uint8_t As[64 * 256];
    __shared__ alignas(16) uint8_t Bs[64 * 256];
    int b = blockIdx.x;
    if (b < 64) {
        gemm64_body(As, Bs, c_bf, c_bf, sim, 0, 512, 512, 1024, 512, 1.0f, b & 7, b >> 3, false);
    } else if (b < 192) {
        b -= 64;
        gemm64_body(As, Bs, fcw_bf, c_bf, W3T, 1, 1000, 512, 1024, 512, 16.0f, b & 7, b >> 3, true);
    } else {
        b -= 192;
        gemm64_body(As, Bs, c_bf, P2, W2T, 1, 512, 1024, 1024, 1024, 16.0f, b & 15, b >> 4, false);
    }
}

// --------- sparsemax rows of 512 (Newton), in-place f32 + fp8(x32) copy + rn zero ---
__global__ __launch_bounds__(256) void sparsemax_k(float* __restrict__ S,
                                                   uint8_t* __restrict__ A8,
                                                   float* __restrict__ rn) {
    int wave = threadIdx.x >> 6, lane = threadIdx.x & 63;
    int row = blockIdx.x * 4 + wave;
    float* z = S + (size_t)row * 512;
    float v[8];
    #pragma unroll
    for (int j = 0; j < 8; j++) v[j] = z[lane + 64 * j];
    float mx = v[0];
    #pragma unroll
    for (int j = 1; j < 8; j++) mx = fmaxf(mx, v[j]);
    #pragma unroll
    for (int off = 1; off < 64; off <<= 1) mx = fmaxf(mx, __shfl_xor(mx, off, 64));
    // Newton on f(tau) = sum(max(v - tau, 0)) - 1 (convex piecewise-linear, decreasing).
    // From tau0 = mx - 1 (f >= 0), iterates increase monotonically to the exact root.
    float tau = mx - 1.0f;
    for (int it = 0; it < 12; it++) {
        float s = 0.0f, k = 0.0f;
        #pragma unroll
        for (int j = 0; j < 8; j++) {
            float d = v[j] - tau;
            if (d > 0.0f) { s += d; k += 1.0f; }
        }
        #pragma unroll
        for (int off = 1; off < 64; off <<= 1) {
            s += __shfl_xor(s, off, 64);
            k += __shfl_xor(k, off, 64);
        }
        tau += (s - 1.0f) / k;
    }
    if (lane == 0) rn[row] = 0.0f;
    uint8_t* o8 = A8 + (size_t)row * 512;
    #pragma unroll
    for (int j = 0; j < 8; j++) {
        float o = fmaxf(v[j] - tau, 0.0f);
        z[lane + 64 * j] = o;
        o8[lane + 64 * j] = f2fp8(o * 32.0f);
    }
}

extern "C" void kernel_launch(void* const* d_in, const int* in_sizes, int n_in,
                              void* d_out, int out_size, void* d_ws, size_t ws_size,
                              hipStream_t stream) {
    const float* x        = (const float*)d_in[0];   // [16384,1024]
    const float* concepts = (const float*)d_in[1];   // [512,1024]
    const float* Wq       = (const float*)d_in[2];   // [1024,1024]
    const float* Wk       = (const float*)d_in[3];   // [1024,1024]
    const float* fc_w     = (const float*)d_in[4];   // [1000,1024]
    const float* fc_b     = (const float*)d_in[5];   // [1000]

    const int B = 16384, D = 1024, C = 512, N = 1000;

    float* out  = (float*)d_out;                       // [B,N]
    float* attn = out + (size_t)B * N;                 // [B,C]
    float* sim  = attn + (size_t)B * C;                // [C,C]

    // ---- ws layout (~35 MiB) ----
    uint8_t* w = (uint8_t*)d_ws;
    uint8_t* x_f8    = w;                                        // [B,D]   16 MiB
    uint8_t* attn_f8 = w + (16ull << 20);                        // [B,C]    8 MiB
    ushort*  Wq_bf   = (ushort*)(w + (24ull << 20));             // [D,D]    2 MiB
    ushort*  Wk_bf   = (ushort*)(w + (26ull << 20));             // [D,D]    2 MiB
    ushort*  fcw_bf  = (ushort*)(w + (28ull << 20));             // [N,D]    2 MiB
    ushort*  c_bf    = (ushort*)(w + (30ull << 20));             // [C,D]    1 MiB
    ushort*  P2_bf   = (ushort*)(w + (31ull << 20));             // [D,D]    2 MiB
    uint8_t* cT_f8   = w + (33ull << 20);                        // [D,C]  0.5 MiB
    uint8_t* W2T_f8  = w + (33ull << 20) + (512ull << 10);       // [C,D]  0.5 MiB
    uint8_t* W3T_f8  = w + (34ull << 20);                        // [N,C]  0.5 MiB
    float*   rn      = (float*)(w + (34ull << 20) + (512ull << 10)); // [B] 64 KiB

    // Reassociation: scores = x @ W2T^T where W2T = c @ (Wq Wk^T)^T  (P2 = Wq @ Wk^T)
    //                out    = (attn @ W3T^T) * rsqrt(|attn@c|^2) + b (W3T = fcw @ c^T)
    // scales: x*1, W2T*16 -> scores scale (1/32)/16 = 1/512 (f32)
    //         attn*32, cT*16 -> rn gemm scale 1/512 (sumsq only)
    //         attn*32, W3T*16 -> out scale 1/512, * rsqrt(rn), + bias

    // 1. all elementwise prep in one launch
    prep_all<<<19960, 256, 0, stream>>>(x, Wq, Wk, fc_w, concepts,
                                        x_f8, Wq_bf, Wk_bf, fcw_bf, c_bf, cT_f8);
    // 2. P2 = Wq @ Wk^T
    gemm_p2<<<dim3(16, 16), 256, 0, stream>>>(Wq_bf, Wk_bf, P2_bf);
    // 3. sim + W3T + W2T in one launch
    gemm_batch3<<<320, 256, 0, stream>>>(c_bf, fcw_bf, P2_bf, sim, W3T_f8, W2T_f8);
    // 4. scores = (x @ W2)/32 -> attn slot of d_out (f32)
    gemm_f8<float, false, false, false, true><<<dim3(C / 128, B / 128), 256, 0, stream>>>(
        x_f8, W2T_f8, nullptr, nullptr, attn, B, C, D, C, 1.0f / 512.0f);
    // 5. sparsemax in place + fp8(*32) copy + rn zero
    sparsemax_k<<<B / 4, 256, 0, stream>>>(attn, attn_f8, rn);
    // 6. rn = rowwise |attn @ c|^2 (sumsq only, no store)
    gemm_f8<uint8_t, false, true, false, false><<<dim3(D / 128, B / 128), 256, 0, stream>>>(
        attn_f8, cT_f8, nullptr, rn, nullptr, B, D, C, D, 1.0f / 512.0f);
    // 7. out = (attn @ W3) * rsqrt(rn) + fc_b
    gemm_f8<float, true, false, true, true><<<dim3((N + 127) / 128, B / 128), 256, 0, stream>>>(
        attn_f8, W3T_f8, fc_b, rn, out, B, N, C, N, 1.0f / 512.0f);
}

// Round 4
// 272.459 us; speedup vs baseline: 1.1780x; 1.0007x over previous
//
#include <hip/hip_runtime.h>
#include <hip/hip_bf16.h>
#include <stdint.h>

typedef __attribute__((ext_vector_type(8))) short short8;
typedef __attribute__((ext_vector_type(4))) float floatx4;
typedef __attribute__((ext_vector_type(8))) int int8v;
typedef __attribute__((ext_vector_type(4))) int int4v;

__device__ __forceinline__ ushort f2b(float f) {
    union { float f; uint32_t u; } v; v.f = f;
    uint32_t r = (v.u + 0x7fffu + ((v.u >> 16) & 1u)) >> 16;
    return (ushort)r;
}
__device__ __forceinline__ float b2f(ushort b) {
    union { uint32_t u; float f; } v; v.u = ((uint32_t)b) << 16;
    return v.f;
}
__device__ __forceinline__ uint8_t f2fp8(float f) {
    return (uint8_t)(__builtin_amdgcn_cvt_pk_fp8_f32(f, f, 0, false) & 0xff);
}

__device__ __forceinline__ void gl_lds16(const void* g, void* l) {
    __builtin_amdgcn_global_load_lds(
        (const __attribute__((address_space(1))) void*)g,
        (__attribute__((address_space(3))) void*)l, 16, 0, 0);
}

// ================= prep mega-kernel: all elementwise/transpose prep in ONE launch ====
// block ranges:
//   [0,16384)        : x f32 -> fp8            (16M elems, 1024/block)
//   [16384,17408)    : Wq f32 -> bf16
//   [17408,18432)    : Wk f32 -> bf16
//   [18432,19432)    : fc_w f32 -> bf16
//   [19432,19944)    : concepts row b: L2-normalize -> c_bf (one row/block)
//   [19944,19960)    : cT_f8 transpose blocks (32 rows x 1024 cols each, inline norms)
__global__ __launch_bounds__(256) void prep_all(
    const float* __restrict__ x, const float* __restrict__ Wq,
    const float* __restrict__ Wk, const float* __restrict__ fcw,
    const float* __restrict__ concepts,
    uint8_t* __restrict__ x_f8, ushort* __restrict__ Wq_bf,
    ushort* __restrict__ Wk_bf, ushort* __restrict__ fcw_bf,
    ushort* __restrict__ c_bf, uint8_t* __restrict__ cT_f8)
{
    __shared__ float smem_f[8];
    __shared__ float partial[32][8];
    __shared__ float invn[32];
    __shared__ uint8_t tile8[32 * 1044];   // stride 1044: 4B-aligned; 261 odd mod 32 -> conflict-free column reads

    int b = blockIdx.x;
    const int tid = threadIdx.x;

    if (b < 16384) {                       // x -> fp8
        int i = b * 256 + tid;
        float4 v = ((const float4*)x)[i];
        int p = __builtin_amdgcn_cvt_pk_fp8_f32(v.x, v.y, 0, false);
        p = __builtin_amdgcn_cvt_pk_fp8_f32(v.z, v.w, p, true);
        ((uint32_t*)x_f8)[i] = p;
        return;
    }
    b -= 16384;
    if (b < 1024) {                        // Wq -> bf16
        int i = b * 256 + tid;
        float4 v = ((const float4*)Wq)[i];
        ushort4 o; o.x = f2b(v.x); o.y = f2b(v.y); o.z = f2b(v.z); o.w = f2b(v.w);
        ((ushort4*)Wq_bf)[i] = o;
        return;
    }
    b -= 1024;
    if (b < 1024) {                        // Wk -> bf16
        int i = b * 256 + tid;
        float4 v = ((const float4*)Wk)[i];
        ushort4 o; o.x = f2b(v.x); o.y = f2b(v.y); o.z = f2b(v.z); o.w = f2b(v.w);
        ((ushort4*)Wk_bf)[i] = o;
        return;
    }
    b -= 1024;
    if (b < 1000) {                        // fc_w -> bf16
        int i = b * 256 + tid;
        float4 v = ((const float4*)fcw)[i];
        ushort4 o; o.x = f2b(v.x); o.y = f2b(v.y); o.z = f2b(v.z); o.w = f2b(v.w);
        ((ushort4*)fcw_bf)[i] = o;
        return;
    }
    b -= 1000;
    if (b < 512) {                         // concept row L2-normalize -> bf16
        const float* xr = concepts + (size_t)b * 1024;
        float vv[4]; float s = 0.0f;
        #pragma unroll
        for (int j = 0; j < 4; j++) { vv[j] = xr[tid + 256 * j]; s += vv[j] * vv[j]; }
        #pragma unroll
        for (int off = 32; off; off >>= 1) s += __shfl_down(s, off, 64);
        if ((tid & 63) == 0) smem_f[tid >> 6] = s;
        __syncthreads();
        float inv = rsqrtf(smem_f[0] + smem_f[1] + smem_f[2] + smem_f[3]);
        ushort* o = c_bf + (size_t)b * 1024;
        #pragma unroll
        for (int j = 0; j < 4; j++) o[tid + 256 * j] = f2b(vv[j] * inv);
        return;
    }
    b -= 512;
    {                                      // cT_f8: rows r0..r0+31, all 1024 cols
        const int r0 = b * 32;
        {
            int row = tid >> 3, sub = tid & 7;
            const float* rp = concepts + (size_t)(r0 + row) * 1024 + sub * 128;
            float s = 0.0f;
            #pragma unroll
            for (int j = 0; j < 32; j++) {
                float4 v = ((const float4*)rp)[j];
                s += v.x * v.x + v.y * v.y + v.z * v.z + v.w * v.w;
            }
            partial[row][sub] = s;
        }
        __syncthreads();
        if (tid < 32) {
            float t = 0.0f;
            #pragma unroll
            for (int j = 0; j < 8; j++) t += partial[tid][j];
            invn[tid] = rsqrtf(t);
        }
        __syncthreads();
        for (int idx = tid; idx < 32 * 256; idx += 256) {
            int row = idx >> 8, d4 = idx & 255;
            float4 v = ((const float4*)(concepts + (size_t)(r0 + row) * 1024))[d4];
            float sc = invn[row] * 16.0f;
            int p = __builtin_amdgcn_cvt_pk_fp8_f32(v.x * sc, v.y * sc, 0, false);
            p = __builtin_amdgcn_cvt_pk_fp8_f32(v.z * sc, v.w * sc, p, true);
            *(uint32_t*)&tile8[row * 1044 + d4 * 4] = p;
        }
        __syncthreads();
        for (int idx = tid; idx < 32 * 1024; idx += 256) {
            int d = idx >> 5, row = idx & 31;
            cT_f8[(size_t)d * 512 + r0 + row] = tile8[row * 1044 + d];
        }
    }
}

// =============== MX-fp8 MFMA GEMM: C = scale*(A @ B^T) [+bias][*rsqrt(rn)] ==========
template<typename OutT, bool NGUARD, bool SUMSQ, bool ROWSCALE, bool STORE>
__global__ __launch_bounds__(256, 3) void gemm_f8(
    const uint8_t* __restrict__ A, const uint8_t* __restrict__ B,
    const float* __restrict__ bias, float* __restrict__ rn, OutT* __restrict__ C,
    int M, int N, int K, int Nld, float scale)
{
    __shared__ alignas(16) uint8_t As[128 * 128];
    __shared__ alignas(16) uint8_t Bs[128 * 128];
    const int id = threadIdx.x;
    const int wave = id >> 6, lane = id & 63;

    int bxi = blockIdx.x, byi = blockIdx.y;
    if ((gridDim.y & 7) == 0) {
        int i = byi * gridDim.x + bxi;
        int xcd = i & 7;
        int j = i >> 3;
        bxi = j % gridDim.x;
        byi = xcd + 8 * (j / gridDim.x);
    }
    const int row0 = byi * 128, col0 = bxi * 128;
    const int wm = (wave >> 1) * 64, wn = (wave & 1) * 64;

    const int fr = id >> 3;
    const int fss = (id & 7) ^ (fr & 7);
    const uint8_t* Agp[4];
    const uint8_t* Bgp[4];
    #pragma unroll
    for (int t = 0; t < 4; t++) {
        int ar = row0 + fr + 32 * t;
        int br = col0 + fr + 32 * t;
        if (NGUARD) br = min(br, N - 1);
        Agp[t] = A + (size_t)ar * K + fss * 16;
        Bgp[t] = B + (size_t)br * K + fss * 16;
    }

    floatx4 acc[4][4] = {};
    const int mrow = lane & 15;
    const int g2 = (lane >> 4) * 2;

    for (int k0 = 0; k0 < K; k0 += 128) {
        #pragma unroll
        for (int t = 0; t < 4; t++) {
            gl_lds16(Agp[t] + k0, &As[id * 16 + 4096 * t]);
            gl_lds16(Bgp[t] + k0, &Bs[id * 16 + 4096 * t]);
        }
        __syncthreads();
        int8v a[4], b[4];
        #pragma unroll
        for (int i = 0; i < 4; i++) {
            int r = wm + i * 16 + mrow, rs = r & 7;
            int4v lo = *(const int4v*)&As[r * 128 + ((g2    ) ^ rs) * 16];
            int4v hi = *(const int4v*)&As[r * 128 + ((g2 + 1) ^ rs) * 16];
            a[i] = __builtin_shufflevector(lo, hi, 0, 1, 2, 3, 4, 5, 6, 7);
        }
        #pragma unroll
        for (int j = 0; j < 4; j++) {
            int r = wn + j * 16 + mrow, rs = r & 7;
            int4v lo = *(const int4v*)&Bs[r * 128 + ((g2    ) ^ rs) * 16];
            int4v hi = *(const int4v*)&Bs[r * 128 + ((g2 + 1) ^ rs) * 16];
            b[j] = __builtin_shufflevector(lo, hi, 0, 1, 2, 3, 4, 5, 6, 7);
        }
        #pragma unroll
        for (int i = 0; i < 4; i++)
            #pragma unroll
            for (int j = 0; j < 4; j++)
                acc[i][j] = __builtin_amdgcn_mfma_scale_f32_16x16x128_f8f6f4(
                    a[i], b[j], acc[i][j], 0, 0, 0, 0x7f7f7f7f, 0, 0x7f7f7f7f);
        __syncthreads();
    }

    const int ccol0 = col0 + wn + (lane & 15);
    const int crow0 = row0 + wm + (lane >> 4) * 4;
    float bv[4];
    #pragma unroll
    for (int j = 0; j < 4; j++) {
        int col = ccol0 + j * 16;
        bv[j] = (bias && (!NGUARD || col < N)) ? bias[col] : 0.0f;
    }
    #pragma unroll
    for (int i = 0; i < 4; i++) {
        #pragma unroll
        for (int r = 0; r < 4; r++) {
            const int row = crow0 + i * 16 + r;
            float inv = 1.0f;
            if constexpr (ROWSCALE) inv = rsqrtf(rn[row]);
            float ss = 0.0f;
            #pragma unroll
            for (int j = 0; j < 4; j++) {
                int col = ccol0 + j * 16;
                float v = acc[i][j][r] * scale * inv + bv[j];
                if constexpr (SUMSQ) ss += v * v;
                if constexpr (STORE) {
                    if (!NGUARD || col < N) {
                        if constexpr (sizeof(OutT) == 1)      C[(size_t)row * Nld + col] = (OutT)f2fp8(v);
                        else if constexpr (sizeof(OutT) == 2) C[(size_t)row * Nld + col] = (OutT)f2b(v);
                        else                                   C[(size_t)row * Nld + col] = v;
                    }
                }
            }
            if constexpr (SUMSQ) {
                #pragma unroll
                for (int m = 1; m < 16; m <<= 1) ss += __shfl_xor(ss, m, 64);
                if ((lane & 15) == 0) atomicAdd(&rn[row], ss);
            }
        }
    }
}

// =============== shared 64x64 bf16 GEMM body: C = scale*(A @ B^T) ==========
// outmode: 0 = f32, 1 = fp8, 2 = bf16
__device__ __forceinline__ void gemm64_body(
    uint8_t* As, uint8_t* Bs,
    const ushort* __restrict__ A, const ushort* __restrict__ B, void* Cout, int outmode,
    int M, int N, int K, int Nld, float scale, int bx, int by, bool mguard)
{
    const int id = threadIdx.x;
    const int wave = id >> 6, lane = id & 63;
    const int row0 = by * 64, col0 = bx * 64;
    const int wm = (wave >> 1) * 32, wn = (wave & 1) * 32;

    const int fr = id >> 4;
    const int sch = (id & 15) ^ (fr & 7);
    const uint8_t* Ab = (const uint8_t*)A;
    const uint8_t* Bb = (const uint8_t*)B;
    const uint8_t* Agp[4];
    const uint8_t* Bgp[4];
    #pragma unroll
    for (int t = 0; t < 4; t++) {
        int ar = row0 + fr + 16 * t;
        if (mguard) ar = min(ar, M - 1);
        int br = col0 + fr + 16 * t;
        Agp[t] = Ab + (size_t)ar * (K * 2) + sch * 16;
        Bgp[t] = Bb + (size_t)br * (K * 2) + sch * 16;
    }

    floatx4 acc[2][2] = {};
    const int mrow = lane & 15, g = lane >> 4;

    for (int k0 = 0; k0 < K; k0 += 128) {
        #pragma unroll
        for (int t = 0; t < 4; t++) {
            gl_lds16(Agp[t] + (size_t)k0 * 2, &As[id * 16 + 4096 * t]);
            gl_lds16(Bgp[t] + (size_t)k0 * 2, &Bs[id * 16 + 4096 * t]);
        }
        __syncthreads();
        #pragma unroll
        for (int ks = 0; ks < 4; ks++) {
            short8 a[2], b[2];
            #pragma unroll
            for (int i = 0; i < 2; i++) {
                int r = wm + i * 16 + mrow;
                a[i] = *(const short8*)&As[r * 256 + ((ks * 4 + g) ^ (r & 7)) * 16];
            }
            #pragma unroll
            for (int j = 0; j < 2; j++) {
                int r = wn + j * 16 + mrow;
                b[j] = *(const short8*)&Bs[r * 256 + ((ks * 4 + g) ^ (r & 7)) * 16];
            }
            #pragma unroll
            for (int i = 0; i < 2; i++)
                #pragma unroll
                for (int j = 0; j < 2; j++)
                    acc[i][j] = __builtin_amdgcn_mfma_f32_16x16x32_bf16(a[i], b[j], acc[i][j], 0, 0, 0);
        }
        __syncthreads();
    }

    const int ccol0 = col0 + wn + (lane & 15);
    const int crow0 = row0 + wm + (lane >> 4) * 4;
    #pragma unroll
    for (int i = 0; i < 2; i++) {
        #pragma unroll
        for (int r = 0; r < 4; r++) {
            const int row = crow0 + i * 16 + r;
            if (mguard && row >= M) continue;
            #pragma unroll
            for (int j = 0; j < 2; j++) {
                int col = ccol0 + j * 16;
                float v = acc[i][j][r] * scale;
                if (outmode == 0)      ((float*)Cout)[(size_t)row * Nld + col] = v;
                else if (outmode == 1) ((uint8_t*)Cout)[(size_t)row * Nld + col] = f2fp8(v);
                else                   ((ushort*)Cout)[(size_t)row * Nld + col] = f2b(v);
            }
        }
    }
}

// P2 = Wq @ Wk^T   [1024,1024] bf16
__global__ __launch_bounds__(256) void gemm_p2(const ushort* __restrict__ Wq_bf,
                                               const ushort* __restrict__ Wk_bf,
                                               ushort* __restrict__ P2) {
    __shared__ alignas(16) uint8_t As[64 * 256];
    __shared__ alignas(16) uint8_t Bs[64 * 256];
    gemm64_body(As, Bs, Wq_bf, Wk_bf, P2, 2, 1024, 1024, 1024, 1024, 1.0f,
                blockIdx.x, blockIdx.y, false);
}

// batched: sim = c@c^T (f32) | W3T = fcw@c^T (fp8*16) | W2T = c@P2^T (fp8*16)
__global__ __launch_bounds__(256) void gemm_batch3(
    const ushort* __restrict__ c_bf, const ushort* __restrict__ fcw_bf,
    const ushort* __restrict__ P2,
    float* __restrict__ sim, uint8_t* __restrict__ W3T, uint8_t* __restrict__ W2T)
{
    __shared__ alignas(16) uint8_t As[64 * 256];
    __shared__ alignas(16) uint8_t Bs[64 * 256];
    int b = blockIdx.x;
    if (b < 64) {
        gemm64_body(As, Bs, c_bf, c_bf, sim, 0, 512, 512, 1024, 512, 1.0f, b & 7, b >> 3, false);
    } else if (b < 192) {
        b -= 64;
        gemm64_body(As, Bs, fcw_bf, c_bf, W3T, 1, 1000, 512, 1024, 512, 16.0f, b & 7, b >> 3, true);
    } else {
        b -= 192;
        gemm64_body(As, Bs, c_bf, P2, W2T, 1, 512, 1024, 1024, 1024, 16.0f, b & 15, b >> 4, false);
    }
}

// ========== fused scores + sparsemax: 64 rows x all 512 cols per block ==========
// scores = (x_f8 @ W2T^T)/512; sparsemax per row fully wave-local (Newton);
// writes attn f32, attn_f8 (*32), rn=0.  Grid 256 blocks, 4 waves each;
// wave w owns rows [w*16, w*16+16) of the block across all 512 cols (acc[32]).
__global__ __launch_bounds__(256, 1) void scores_sparsemax(
    const uint8_t* __restrict__ X, const uint8_t* __restrict__ W2T,
    float* __restrict__ attn, uint8_t* __restrict__ A8, float* __restrict__ rn)
{
    __shared__ alignas(16) uint8_t As[64 * 128];
    __shared__ alignas(16) uint8_t Bs[512 * 128];
    const int id = threadIdx.x;
    const int wave = id >> 6, lane = id & 63;
    const int row0 = blockIdx.x * 64;

    const int fr = id >> 3;                    // 0..31
    const int fss = (id & 7) ^ (fr & 7);       // XOR-swizzled source chunk
    const uint8_t* Ag = X + (size_t)(row0 + fr) * 1024 + fss * 16;
    const uint8_t* Bg = W2T + (size_t)fr * 1024 + fss * 16;

    floatx4 acc[32] = {};
    const int mrow = lane & 15;
    const int g2 = (lane >> 4) * 2;
    const int arow = wave * 16 + mrow;
    const int ars = arow & 7;

    for (int k0 = 0; k0 < 1024; k0 += 128) {
        #pragma unroll
        for (int t = 0; t < 2; t++)
            gl_lds16(Ag + k0 + t * 32 * 1024, &As[id * 16 + 4096 * t]);
        #pragma unroll
        for (int t = 0; t < 16; t++)
            gl_lds16(Bg + k0 + t * 32 * 1024, &Bs[id * 16 + 4096 * t]);
        __syncthreads();
        int4v alo = *(const int4v*)&As[arow * 128 + ((g2    ) ^ ars) * 16];
        int4v ahi = *(const int4v*)&As[arow * 128 + ((g2 + 1) ^ ars) * 16];
        int8v a = __builtin_shufflevector(alo, ahi, 0, 1, 2, 3, 4, 5, 6, 7);
        #pragma unroll
        for (int j = 0; j < 32; j++) {
            int rb = j * 16 + mrow, rs = rb & 7;
            int4v lo = *(const int4v*)&Bs[rb * 128 + ((g2    ) ^ rs) * 16];
            int4v hi = *(const int4v*)&Bs[rb * 128 + ((g2 + 1) ^ rs) * 16];
            int8v b = __builtin_shufflevector(lo, hi, 0, 1, 2, 3, 4, 5, 6, 7);
            acc[j] = __builtin_amdgcn_mfma_scale_f32_16x16x128_f8f6f4(
                a, b, acc[j], 0, 0, 0, 0x7f7f7f7f, 0, 0x7f7f7f7f);
        }
        __syncthreads();
    }

    // scale to true scores
    #pragma unroll
    for (int j = 0; j < 32; j++) acc[j] = acc[j] * (1.0f / 512.0f);

    // per-row max (rows g*4+r live across the 16 lanes of group g = lane>>4)
    float tau_[4];
    #pragma unroll
    for (int r = 0; r < 4; r++) {
        float m = acc[0][r];
        #pragma unroll
        for (int j = 1; j < 32; j++) m = fmaxf(m, acc[j][r]);
        #pragma unroll
        for (int off = 1; off < 16; off <<= 1) m = fmaxf(m, __shfl_xor(m, off, 64));
        tau_[r] = m - 1.0f;
    }
    // Newton on f(tau) = sum(max(v-tau,0)) - 1: monotone convergence from below; k>=1 always.
    for (int it = 0; it < 12; it++) {
        float s0 = 0, s1 = 0, s2 = 0, s3 = 0, k0_ = 0, k1_ = 0, k2_ = 0, k3_ = 0;
        #pragma unroll
        for (int j = 0; j < 32; j++) {
            float d0 = acc[j][0] - tau_[0]; if (d0 > 0.0f) { s0 += d0; k0_ += 1.0f; }
            float d1 = acc[j][1] - tau_[1]; if (d1 > 0.0f) { s1 += d1; k1_ += 1.0f; }
            float d2 = acc[j][2] - tau_[2]; if (d2 > 0.0f) { s2 += d2; k2_ += 1.0f; }
            float d3 = acc[j][3] - tau_[3]; if (d3 > 0.0f) { s3 += d3; k3_ += 1.0f; }
        }
        #pragma unroll
        for (int off = 1; off < 16; off <<= 1) {
            s0 += __shfl_xor(s0, off, 64); k0_ += __shfl_xor(k0_, off, 64);
            s1 += __shfl_xor(s1, off, 64); k1_ += __shfl_xor(k1_, off, 64);
            s2 += __shfl_xor(s2, off, 64); k2_ += __shfl_xor(k2_, off, 64);
            s3 += __shfl_xor(s3, off, 64); k3_ += __shfl_xor(k3_, off, 64);
        }
        tau_[0] += (s0 - 1.0f) / k0_;
        tau_[1] += (s1 - 1.0f) / k1_;
        tau_[2] += (s2 - 1.0f) / k2_;
        tau_[3] += (s3 - 1.0f) / k3_;
    }

    const int rbase = row0 + wave * 16 + (lane >> 4) * 4;
    const int cbase = lane & 15;
    if (cbase == 0) {
        #pragma unroll
        for (int r = 0; r < 4; r++) rn[rbase + r] = 0.0f;
    }
    #pragma unroll
    for (int r = 0; r < 4; r++) {
        float* zo = attn + (size_t)(rbase + r) * 512 + cbase;
        uint8_t* o8 = A8 + (size_t)(rbase + r) * 512 + cbase;
        #pragma unroll
        for (int j = 0; j < 32; j++) {
            float o = fmaxf(acc[j][r] - tau_[r], 0.0f);
            zo[16 * j] = o;
            o8[16 * j] = f2fp8(o * 32.0f);
        }
    }
}

extern "C" void kernel_launch(void* const* d_in, const int* in_sizes, int n_in,
                              void* d_out, int out_size, void* d_ws, size_t ws_size,
                              hipStream_t stream) {
    const float* x        = (const float*)d_in[0];   // [16384,1024]
    const float* concepts = (const float*)d_in[1];   // [512,1024]
    const float* Wq       = (const float*)d_in[2];   // [1024,1024]
    const float* Wk       = (const float*)d_in[3];   // [1024,1024]
    const float* fc_w     = (const float*)d_in[4];   // [1000,1024]
    const float* fc_b     = (const float*)d_in[5];   // [1000]

    const int B = 16384, D = 1024, C = 512, N = 1000;

    float* out  = (float*)d_out;                       // [B,N]
    float* attn = out + (size_t)B * N;                 // [B,C]
    float* sim  = attn + (size_t)B * C;                // [C,C]

    // ---- ws layout (~35 MiB) ----
    uint8_t* w = (uint8_t*)d_ws;
    uint8_t* x_f8    = w;                                        // [B,D]   16 MiB
    uint8_t* attn_f8 = w + (16ull << 20);                        // [B,C]    8 MiB
    ushort*  Wq_bf   = (ushort*)(w + (24ull << 20));             // [D,D]    2 MiB
    ushort*  Wk_bf   = (ushort*)(w + (26ull << 20));             // [D,D]    2 MiB
    ushort*  fcw_bf  = (ushort*)(w + (28ull << 20));             // [N,D]    2 MiB
    ushort*  c_bf    = (ushort*)(w + (30ull << 20));             // [C,D]    1 MiB
    ushort*  P2_bf   = (ushort*)(w + (31ull << 20));             // [D,D]    2 MiB
    uint8_t* cT_f8   = w + (33ull << 20);                        // [D,C]  0.5 MiB
    uint8_t* W2T_f8  = w + (33ull << 20) + (512ull << 10);       // [C,D]  0.5 MiB
    uint8_t* W3T_f8  = w + (34ull << 20);                        // [N,C]  0.5 MiB
    float*   rn      = (float*)(w + (34ull << 20) + (512ull << 10)); // [B] 64 KiB

    // Reassociation: scores = x @ W2T^T where W2T = c @ (Wq Wk^T)^T  (P2 = Wq @ Wk^T)
    //                out    = (attn @ W3T^T) * rsqrt(|attn@c|^2) + b (W3T = fcw @ c^T)
    // scales: x*1, W2T*16 -> scores scale (1/32)/16 = 1/512 (f32)
    //         attn*32, cT*16 -> rn gemm scale 1/512 (sumsq only)
    //         attn*32, W3T*16 -> out scale 1/512, * rsqrt(rn), + bias

    // 1. all elementwise prep in one launch
    prep_all<<<19960, 256, 0, stream>>>(x, Wq, Wk, fc_w, concepts,
                                        x_f8, Wq_bf, Wk_bf, fcw_bf, c_bf, cT_f8);
    // 2. P2 = Wq @ Wk^T
    gemm_p2<<<dim3(16, 16), 256, 0, stream>>>(Wq_bf, Wk_bf, P2_bf);
    // 3. sim + W3T + W2T in one launch
    gemm_batch3<<<320, 256, 0, stream>>>(c_bf, fcw_bf, P2_bf, sim, W3T_f8, W2T_f8);
    // 4. fused scores + sparsemax -> attn (f32), attn_f8 (*32), rn = 0
    scores_sparsemax<<<B / 64, 256, 0, stream>>>(x_f8, W2T_f8, attn, attn_f8, rn);
    // 5. rn = rowwise |attn @ c|^2 (sumsq only, no store)
    gemm_f8<uint8_t, false, true, false, false><<<dim3(D / 128, B / 128), 256, 0, stream>>>(
        attn_f8, cT_f8, nullptr, rn, nullptr, B, D, C, D, 1.0f / 512.0f);
    // 6. out = (attn @ W3) * rsqrt(rn) + fc_b
    gemm_f8<float, true, false, true, true><<<dim3((N + 127) / 128, B / 128), 256, 0, stream>>>(
        attn_f8, W3T_f8, fc_b, rn, out, B, N, C, N, 1.0f / 512.0f);
}

// Round 6
// 268.398 us; speedup vs baseline: 1.1958x; 1.0151x over previous
//
#include <hip/hip_runtime.h>
#include <hip/hip_bf16.h>
#include <stdint.h>

typedef __attribute__((ext_vector_type(8))) short short8;
typedef __attribute__((ext_vector_type(4))) float floatx4;
typedef __attribute__((ext_vector_type(8))) int int8v;
typedef __attribute__((ext_vector_type(4))) int int4v;

__device__ __forceinline__ ushort f2b(float f) {
    union { float f; uint32_t u; } v; v.f = f;
    uint32_t r = (v.u + 0x7fffu + ((v.u >> 16) & 1u)) >> 16;
    return (ushort)r;
}
__device__ __forceinline__ float b2f(ushort b) {
    union { uint32_t u; float f; } v; v.u = ((uint32_t)b) << 16;
    return v.f;
}
__device__ __forceinline__ uint8_t f2fp8(float f) {
    return (uint8_t)(__builtin_amdgcn_cvt_pk_fp8_f32(f, f, 0, false) & 0xff);
}

__device__ __forceinline__ void gl_lds16(const void* g, void* l) {
    __builtin_amdgcn_global_load_lds(
        (const __attribute__((address_space(1))) void*)g,
        (__attribute__((address_space(3))) void*)l, 16, 0, 0);
}

// ================= prep mega-kernel: all elementwise/transpose prep in ONE launch ====
// block ranges: x->fp8 | Wq->bf16 | Wk->bf16 | fcw->bf16 | concept-normalize |
//               cT_f8 transpose | W3T tail-rows zero
__global__ __launch_bounds__(256) void prep_all(
    const float* __restrict__ x, const float* __restrict__ Wq,
    const float* __restrict__ Wk, const float* __restrict__ fcw,
    const float* __restrict__ concepts,
    uint8_t* __restrict__ x_f8, ushort* __restrict__ Wq_bf,
    ushort* __restrict__ Wk_bf, ushort* __restrict__ fcw_bf,
    ushort* __restrict__ c_bf, uint8_t* __restrict__ cT_f8,
    uint8_t* __restrict__ W3T_f8)
{
    __shared__ float smem_f[8];
    __shared__ float partial[32][8];
    __shared__ float invn[32];
    __shared__ uint8_t tile8[32 * 1044];   // stride 1044: 4B-aligned; 261 odd mod 32 -> conflict-free column reads

    int b = blockIdx.x;
    const int tid = threadIdx.x;

    if (b < 16384) {                       // x -> fp8
        int i = b * 256 + tid;
        float4 v = ((const float4*)x)[i];
        int p = __builtin_amdgcn_cvt_pk_fp8_f32(v.x, v.y, 0, false);
        p = __builtin_amdgcn_cvt_pk_fp8_f32(v.z, v.w, p, true);
        ((uint32_t*)x_f8)[i] = p;
        return;
    }
    b -= 16384;
    if (b < 1024) {                        // Wq -> bf16
        int i = b * 256 + tid;
        float4 v = ((const float4*)Wq)[i];
        ushort4 o; o.x = f2b(v.x); o.y = f2b(v.y); o.z = f2b(v.z); o.w = f2b(v.w);
        ((ushort4*)Wq_bf)[i] = o;
        return;
    }
    b -= 1024;
    if (b < 1024) {                        // Wk -> bf16
        int i = b * 256 + tid;
        float4 v = ((const float4*)Wk)[i];
        ushort4 o; o.x = f2b(v.x); o.y = f2b(v.y); o.z = f2b(v.z); o.w = f2b(v.w);
        ((ushort4*)Wk_bf)[i] = o;
        return;
    }
    b -= 1024;
    if (b < 1000) {                        // fc_w -> bf16
        int i = b * 256 + tid;
        float4 v = ((const float4*)fcw)[i];
        ushort4 o; o.x = f2b(v.x); o.y = f2b(v.y); o.z = f2b(v.z); o.w = f2b(v.w);
        ((ushort4*)fcw_bf)[i] = o;
        return;
    }
    b -= 1000;
    if (b < 512) {                         // concept row L2-normalize -> bf16
        const float* xr = concepts + (size_t)b * 1024;
        float vv[4]; float s = 0.0f;
        #pragma unroll
        for (int j = 0; j < 4; j++) { vv[j] = xr[tid + 256 * j]; s += vv[j] * vv[j]; }
        #pragma unroll
        for (int off = 32; off; off >>= 1) s += __shfl_down(s, off, 64);
        if ((tid & 63) == 0) smem_f[tid >> 6] = s;
        __syncthreads();
        float inv = rsqrtf(smem_f[0] + smem_f[1] + smem_f[2] + smem_f[3]);
        ushort* o = c_bf + (size_t)b * 1024;
        #pragma unroll
        for (int j = 0; j < 4; j++) o[tid + 256 * j] = f2b(vv[j] * inv);
        return;
    }
    b -= 512;
    if (b < 16) {                          // cT_f8: rows r0..r0+31, all 1024 cols
        const int r0 = b * 32;
        {
            int row = tid >> 3, sub = tid & 7;
            const float* rp = concepts + (size_t)(r0 + row) * 1024 + sub * 128;
            float s = 0.0f;
            #pragma unroll
            for (int j = 0; j < 32; j++) {
                float4 v = ((const float4*)rp)[j];
                s += v.x * v.x + v.y * v.y + v.z * v.z + v.w * v.w;
            }
            partial[row][sub] = s;
        }
        __syncthreads();
        if (tid < 32) {
            float t = 0.0f;
            #pragma unroll
            for (int j = 0; j < 8; j++) t += partial[tid][j];
            invn[tid] = rsqrtf(t);
        }
        __syncthreads();
        for (int idx = tid; idx < 32 * 256; idx += 256) {
            int row = idx >> 8, d4 = idx & 255;
            float4 v = ((const float4*)(concepts + (size_t)(r0 + row) * 1024))[d4];
            float sc = invn[row] * 16.0f;
            int p = __builtin_amdgcn_cvt_pk_fp8_f32(v.x * sc, v.y * sc, 0, false);
            p = __builtin_amdgcn_cvt_pk_fp8_f32(v.z * sc, v.w * sc, p, true);
            *(uint32_t*)&tile8[row * 1044 + d4 * 4] = p;
        }
        __syncthreads();
        for (int idx = tid; idx < 32 * 1024; idx += 256) {
            int d = idx >> 5, row = idx & 31;
            cT_f8[(size_t)d * 512 + r0 + row] = tile8[row * 1044 + d];
        }
        return;
    }
    {                                      // zero W3T rows 1000..1023 (24*512 B)
        uint32_t* p = (uint32_t*)(W3T_f8 + 1000 * 512);
        #pragma unroll
        for (int k = 0; k < 12; k++) p[tid + 256 * k] = 0u;
    }
}

// =============== MX-fp8 MFMA GEMM: C = scale*(A @ B^T) [+bias][*rsqrt(rn)] ==========
template<typename OutT, bool NGUARD, bool SUMSQ, bool ROWSCALE, bool STORE>
__global__ __launch_bounds__(256, 3) void gemm_f8(
    const uint8_t* __restrict__ A, const uint8_t* __restrict__ B,
    const float* __restrict__ bias, float* __restrict__ rn, OutT* __restrict__ C,
    int M, int N, int K, int Nld, float scale)
{
    __shared__ alignas(16) uint8_t As[128 * 128];
    __shared__ alignas(16) uint8_t Bs[128 * 128];
    const int id = threadIdx.x;
    const int wave = id >> 6, lane = id & 63;

    int bxi = blockIdx.x, byi = blockIdx.y;
    if ((gridDim.y & 7) == 0) {
        int i = byi * gridDim.x + bxi;
        int xcd = i & 7;
        int j = i >> 3;
        bxi = j % gridDim.x;
        byi = xcd + 8 * (j / gridDim.x);
    }
    const int row0 = byi * 128, col0 = bxi * 128;
    const int wm = (wave >> 1) * 64, wn = (wave & 1) * 64;

    const int fr = id >> 3;
    const int fss = (id & 7) ^ (fr & 7);
    const uint8_t* Agp[4];
    const uint8_t* Bgp[4];
    #pragma unroll
    for (int t = 0; t < 4; t++) {
        int ar = row0 + fr + 32 * t;
        int br = col0 + fr + 32 * t;
        if (NGUARD) br = min(br, N - 1);
        Agp[t] = A + (size_t)ar * K + fss * 16;
        Bgp[t] = B + (size_t)br * K + fss * 16;
    }

    floatx4 acc[4][4] = {};
    const int mrow = lane & 15;
    const int g2 = (lane >> 4) * 2;

    for (int k0 = 0; k0 < K; k0 += 128) {
        #pragma unroll
        for (int t = 0; t < 4; t++) {
            gl_lds16(Agp[t] + k0, &As[id * 16 + 4096 * t]);
            gl_lds16(Bgp[t] + k0, &Bs[id * 16 + 4096 * t]);
        }
        __syncthreads();
        int8v a[4], b[4];
        #pragma unroll
        for (int i = 0; i < 4; i++) {
            int r = wm + i * 16 + mrow, rs = r & 7;
            int4v lo = *(const int4v*)&As[r * 128 + ((g2    ) ^ rs) * 16];
            int4v hi = *(const int4v*)&As[r * 128 + ((g2 + 1) ^ rs) * 16];
            a[i] = __builtin_shufflevector(lo, hi, 0, 1, 2, 3, 4, 5, 6, 7);
        }
        #pragma unroll
        for (int j = 0; j < 4; j++) {
            int r = wn + j * 16 + mrow, rs = r & 7;
            int4v lo = *(const int4v*)&Bs[r * 128 + ((g2    ) ^ rs) * 16];
            int4v hi = *(const int4v*)&Bs[r * 128 + ((g2 + 1) ^ rs) * 16];
            b[j] = __builtin_shufflevector(lo, hi, 0, 1, 2, 3, 4, 5, 6, 7);
        }
        #pragma unroll
        for (int i = 0; i < 4; i++)
            #pragma unroll
            for (int j = 0; j < 4; j++)
                acc[i][j] = __builtin_amdgcn_mfma_scale_f32_16x16x128_f8f6f4(
                    a[i], b[j], acc[i][j], 0, 0, 0, 0x7f7f7f7f, 0, 0x7f7f7f7f);
        __syncthreads();
    }

    const int ccol0 = col0 + wn + (lane & 15);
    const int crow0 = row0 + wm + (lane >> 4) * 4;
    float bv[4];
    #pragma unroll
    for (int j = 0; j < 4; j++) {
        int col = ccol0 + j * 16;
        bv[j] = (bias && (!NGUARD || col < N)) ? bias[col] : 0.0f;
    }
    #pragma unroll
    for (int i = 0; i < 4; i++) {
        #pragma unroll
        for (int r = 0; r < 4; r++) {
            const int row = crow0 + i * 16 + r;
            float inv = 1.0f;
            if constexpr (ROWSCALE) inv = rsqrtf(rn[row]);
            float ss = 0.0f;
            #pragma unroll
            for (int j = 0; j < 4; j++) {
                int col = ccol0 + j * 16;
                float v = acc[i][j][r] * scale * inv + bv[j];
                if constexpr (SUMSQ) ss += v * v;
                if constexpr (STORE) {
                    if (!NGUARD || col < N) {
                        if constexpr (sizeof(OutT) == 1)      C[(size_t)row * Nld + col] = (OutT)f2fp8(v);
                        else if constexpr (sizeof(OutT) == 2) C[(size_t)row * Nld + col] = (OutT)f2b(v);
                        else                                   C[(size_t)row * Nld + col] = v;
                    }
                }
            }
            if constexpr (SUMSQ) {
                #pragma unroll
                for (int m = 1; m < 16; m <<= 1) ss += __shfl_xor(ss, m, 64);
                if ((lane & 15) == 0) atomicAdd(&rn[row], ss);
            }
        }
    }
}

// =============== shared 64x64 bf16 GEMM body: C = scale*(A @ B^T) ==========
// outmode: 0 = f32, 1 = fp8, 2 = bf16
__device__ __forceinline__ void gemm64_body(
    uint8_t* As, uint8_t* Bs,
    const ushort* __restrict__ A, const ushort* __restrict__ B, void* Cout, int outmode,
    int M, int N, int K, int Nld, float scale, int bx, int by, bool mguard)
{
    const int id = threadIdx.x;
    const int wave = id >> 6, lane = id & 63;
    const int row0 = by * 64, col0 = bx * 64;
    const int wm = (wave >> 1) * 32, wn = (wave & 1) * 32;

    const int fr = id >> 4;
    const int sch = (id & 15) ^ (fr & 7);
    const uint8_t* Ab = (const uint8_t*)A;
    const uint8_t* Bb = (const uint8_t*)B;
    const uint8_t* Agp[4];
    const uint8_t* Bgp[4];
    #pragma unroll
    for (int t = 0; t < 4; t++) {
        int ar = row0 + fr + 16 * t;
        if (mguard) ar = min(ar, M - 1);
        int br = col0 + fr + 16 * t;
        Agp[t] = Ab + (size_t)ar * (K * 2) + sch * 16;
        Bgp[t] = Bb + (size_t)br * (K * 2) + sch * 16;
    }

    floatx4 acc[2][2] = {};
    const int mrow = lane & 15, g = lane >> 4;

    for (int k0 = 0; k0 < K; k0 += 128) {
        #pragma unroll
        for (int t = 0; t < 4; t++) {
            gl_lds16(Agp[t] + (size_t)k0 * 2, &As[id * 16 + 4096 * t]);
            gl_lds16(Bgp[t] + (size_t)k0 * 2, &Bs[id * 16 + 4096 * t]);
        }
        __syncthreads();
        #pragma unroll
        for (int ks = 0; ks < 4; ks++) {
            short8 a[2], b[2];
            #pragma unroll
            for (int i = 0; i < 2; i++) {
                int r = wm + i * 16 + mrow;
                a[i] = *(const short8*)&As[r * 256 + ((ks * 4 + g) ^ (r & 7)) * 16];
            }
            #pragma unroll
            for (int j = 0; j < 2; j++) {
                int r = wn + j * 16 + mrow;
                b[j] = *(const short8*)&Bs[r * 256 + ((ks * 4 + g) ^ (r & 7)) * 16];
            }
            #pragma unroll
            for (int i = 0; i < 2; i++)
                #pragma unroll
                for (int j = 0; j < 2; j++)
                    acc[i][j] = __builtin_amdgcn_mfma_f32_16x16x32_bf16(a[i], b[j], acc[i][j], 0, 0, 0);
        }
        __syncthreads();
    }

    const int ccol0 = col0 + wn + (lane & 15);
    const int crow0 = row0 + wm + (lane >> 4) * 4;
    #pragma unroll
    for (int i = 0; i < 2; i++) {
        #pragma unroll
        for (int r = 0; r < 4; r++) {
            const int row = crow0 + i * 16 + r;
            if (mguard && row >= M) continue;
            #pragma unroll
            for (int j = 0; j < 2; j++) {
                int col = ccol0 + j * 16;
                float v = acc[i][j][r] * scale;
                if (outmode == 0)      ((float*)Cout)[(size_t)row * Nld + col] = v;
                else if (outmode == 1) ((uint8_t*)Cout)[(size_t)row * Nld + col] = f2fp8(v);
                else                   ((ushort*)Cout)[(size_t)row * Nld + col] = f2b(v);
            }
        }
    }
}

// P2 = Wq @ Wk^T   [1024,1024] bf16
__global__ __launch_bounds__(256) void gemm_p2(const ushort* __restrict__ Wq_bf,
                                               const ushort* __restrict__ Wk_bf,
                                               ushort* __restrict__ P2) {
    __shared__ alignas(16) uint8_t As[64 * 256];
    __shared__ alignas(16) uint8_t Bs[64 * 256];
    gemm64_body(As, Bs, Wq_bf, Wk_bf, P2, 2, 1024, 1024, 1024, 1024, 1.0f,
                blockIdx.x, blockIdx.y, false);
}

// batched: sim = c@c^T (f32) | W3T = fcw@c^T (fp8*16) | W2T = c@P2^T (fp8*16)
__global__ __launch_bounds__(256) void gemm_batch3(
    const ushort* __restrict__ c_bf, const ushort* __restrict__ fcw_bf,
    const ushort* __restrict__ P2,
    float* __restrict__ sim, uint8_t* __restrict__ W3T, uint8_t* __restrict__ W2T)
{
    __shared__ alignas(16) uint8_t As[64 * 256];
    __shared__ alignas(16) uint8_t Bs[64 * 256];
    int b = blockIdx.x;
    if (b < 64) {
        gemm64_body(As, Bs, c_bf, c_bf, sim, 0, 512, 512, 1024, 512, 1.0f, b & 7, b >> 3, false);
    } else if (b < 192) {
        b -= 64;
        gemm64_body(As, Bs, fcw_bf, c_bf, W3T, 1, 1000, 512, 1024, 512, 16.0f, b & 7, b >> 3, true);
    } else {
        b -= 192;
        gemm64_body(As, Bs, c_bf, P2, W2T, 1, 512, 1024, 1024, 1024, 16.0f, b & 15, b >> 4, false);
    }
}

// ===== fused scores + sparsemax + rn: 64 rows per block =====
// Phase 1: scores = (x_f8 @ W2T^T)/512 (wave owns 16 rows x 512 cols, acc[32])  [R4-proven]
// Phase 2: Newton sparsemax (wave-local)                                         [R4-proven]
// Phase 3: attn f32 -> global; attn fp8(*32) -> global A8 AND LDS at8 (XOR-swizzled)
// Phase 4: rn[row] = |attn @ c|^2 via MFMA vs cT 64-row segments (A-frags in regs),
//          reduced in-block, written directly (no atomics). out stays a separate dispatch.
__global__ __launch_bounds__(256, 1) void scores_sm_rn(
    const uint8_t* __restrict__ X, const uint8_t* __restrict__ W2T,
    const uint8_t* __restrict__ cT,
    float* __restrict__ attn, uint8_t* __restrict__ A8, float* __restrict__ rn)
{
    // LDS plan (99328 B): scores: As [0,8192) + Bs [8192,73728)
    //                     rn:     at8 [0,32768) + Bst 2x32768 [32768,98304) + rnred [98304,99328)
    __shared__ alignas(16) uint8_t lds[99328];
    uint8_t* As  = lds;
    uint8_t* Bs  = lds + 8192;
    uint8_t* at8 = lds;
    uint8_t* Bst = lds + 32768;
    float* rnred = (float*)(lds + 98304);

    const int id = threadIdx.x;
    const int wave = id >> 6, lane = id & 63;
    const int row0 = blockIdx.x * 64;
    const int mrow = lane & 15;
    const int g = lane >> 4;
    const int g2 = g * 2;

    // ---------------- phase 1: scores GEMM ----------------
    const int fr = id >> 3;
    const int fss = (id & 7) ^ (fr & 7);
    const uint8_t* Ag = X + (size_t)(row0 + fr) * 1024 + fss * 16;
    const uint8_t* Bg = W2T + (size_t)fr * 1024 + fss * 16;

    floatx4 acc[32] = {};
    {
        const int arow = wave * 16 + mrow;
        const int ars = arow & 7;
        for (int k0 = 0; k0 < 1024; k0 += 128) {
            #pragma unroll
            for (int t = 0; t < 2; t++)
                gl_lds16(Ag + k0 + (size_t)t * 32 * 1024, &As[id * 16 + 4096 * t]);
            #pragma unroll
            for (int t = 0; t < 16; t++)
                gl_lds16(Bg + k0 + (size_t)t * 32 * 1024, &Bs[id * 16 + 4096 * t]);
            __syncthreads();
            int4v alo = *(const int4v*)&As[arow * 128 + ((g2    ) ^ ars) * 16];
            int4v ahi = *(const int4v*)&As[arow * 128 + ((g2 + 1) ^ ars) * 16];
            int8v a = __builtin_shufflevector(alo, ahi, 0, 1, 2, 3, 4, 5, 6, 7);
            #pragma unroll
            for (int j = 0; j < 32; j++) {
                int rb = j * 16 + mrow, rs = rb & 7;
                int4v lo = *(const int4v*)&Bs[rb * 128 + ((g2    ) ^ rs) * 16];
                int4v hi = *(const int4v*)&Bs[rb * 128 + ((g2 + 1) ^ rs) * 16];
                int8v b = __builtin_shufflevector(lo, hi, 0, 1, 2, 3, 4, 5, 6, 7);
                acc[j] = __builtin_amdgcn_mfma_scale_f32_16x16x128_f8f6f4(
                    a, b, acc[j], 0, 0, 0, 0x7f7f7f7f, 0, 0x7f7f7f7f);
            }
            __syncthreads();
        }
    }
    #pragma unroll
    for (int j = 0; j < 32; j++) acc[j] = acc[j] * (1.0f / 512.0f);

    // ---------------- phase 2: sparsemax (Newton) ----------------
    float tau_[4];
    #pragma unroll
    for (int r = 0; r < 4; r++) {
        float m = acc[0][r];
        #pragma unroll
        for (int j = 1; j < 32; j++) m = fmaxf(m, acc[j][r]);
        #pragma unroll
        for (int off = 1; off < 16; off <<= 1) m = fmaxf(m, __shfl_xor(m, off, 64));
        tau_[r] = m - 1.0f;
    }
    for (int it = 0; it < 12; it++) {
        float s0 = 0, s1 = 0, s2 = 0, s3 = 0, k0_ = 0, k1_ = 0, k2_ = 0, k3_ = 0;
        #pragma unroll
        for (int j = 0; j < 32; j++) {
            float d0 = acc[j][0] - tau_[0]; if (d0 > 0.0f) { s0 += d0; k0_ += 1.0f; }
            float d1 = acc[j][1] - tau_[1]; if (d1 > 0.0f) { s1 += d1; k1_ += 1.0f; }
            float d2 = acc[j][2] - tau_[2]; if (d2 > 0.0f) { s2 += d2; k2_ += 1.0f; }
            float d3 = acc[j][3] - tau_[3]; if (d3 > 0.0f) { s3 += d3; k3_ += 1.0f; }
        }
        #pragma unroll
        for (int off = 1; off < 16; off <<= 1) {
            s0 += __shfl_xor(s0, off, 64); k0_ += __shfl_xor(k0_, off, 64);
            s1 += __shfl_xor(s1, off, 64); k1_ += __shfl_xor(k1_, off, 64);
            s2 += __shfl_xor(s2, off, 64); k2_ += __shfl_xor(k2_, off, 64);
            s3 += __shfl_xor(s3, off, 64); k3_ += __shfl_xor(k3_, off, 64);
        }
        tau_[0] += (s0 - 1.0f) / k0_;
        tau_[1] += (s1 - 1.0f) / k1_;
        tau_[2] += (s2 - 1.0f) / k2_;
        tau_[3] += (s3 - 1.0f) / k3_;
    }

    // ------- phase 3: attn f32 -> global, fp8 -> global A8 + LDS at8 (swizzled) -------
    {
        const int rl = wave * 16 + g * 4;
        #pragma unroll
        for (int r = 0; r < 4; r++) {
            const int rr = rl + r;
            const int rsw = rr & 7;
            float* zo = attn + (size_t)(row0 + rr) * 512 + mrow;
            uint8_t* o8 = A8 + (size_t)(row0 + rr) * 512 + mrow;
            uint8_t* a8r = at8 + rr * 512 + mrow;
            #pragma unroll
            for (int j = 0; j < 32; j++) {
                float o = fmaxf(acc[j][r] - tau_[r], 0.0f);
                uint8_t q = f2fp8(o * 32.0f);
                zo[16 * j] = o;
                o8[16 * j] = q;
                a8r[(j ^ rsw) << 4] = q;
            }
        }
    }
    __syncthreads();

    // ---------------- cached A-fragments (attn tile, all 64 rows) ----------------
    int8v a_all[4][4];
    #pragma unroll
    for (int mt = 0; mt < 4; mt++) {
        const int row = mt * 16 + mrow;
        const int rs = row & 7;
        #pragma unroll
        for (int ks = 0; ks < 4; ks++) {
            int4v lo = *(const int4v*)&at8[row * 512 + (((ks * 8 + g2    ) ^ rs) << 4)];
            int4v hi = *(const int4v*)&at8[row * 512 + (((ks * 8 + g2 + 1) ^ rs) << 4)];
            a_all[mt][ks] = __builtin_shufflevector(lo, hi, 0, 1, 2, 3, 4, 5, 6, 7);
        }
    }

    // staging geometry for 64-row B segments ([64][512] fp8, 32 chunks/row)
    const int trow = id >> 5;                  // base row 0..7 (+8t)
    const int tsch = (id & 31) ^ (trow & 7);   // XOR pre-swizzled source chunk (t-invariant)
    const int brow = wave * 16 + mrow;         // this lane's B row within a segment
    const int brs = brow & 7;

    float ss[16] = {};

    // ---------------- phase 4: rn over cT (16 segs, dbuf) ----------------
    #pragma unroll
    for (int t = 0; t < 8; t++)
        gl_lds16(cT + (size_t)(trow + 8 * t) * 512 + tsch * 16, Bst + (id + 256 * t) * 16);
    __syncthreads();
    for (int seg = 0; seg < 16; seg++) {
        const int cur = seg & 1;
        if (seg < 15) {
            #pragma unroll
            for (int t = 0; t < 8; t++)
                gl_lds16(cT + (size_t)((seg + 1) * 64 + trow + 8 * t) * 512 + tsch * 16,
                         Bst + (cur ^ 1) * 32768 + (id + 256 * t) * 16);
        }
        const uint8_t* Bb = Bst + cur * 32768;
        floatx4 acc_t[4] = {};
        #pragma unroll
        for (int ks = 0; ks < 4; ks++) {
            int4v lo = *(const int4v*)&Bb[brow * 512 + (((ks * 8 + g2    ) ^ brs) << 4)];
            int4v hi = *(const int4v*)&Bb[brow * 512 + (((ks * 8 + g2 + 1) ^ brs) << 4)];
            int8v b = __builtin_shufflevector(lo, hi, 0, 1, 2, 3, 4, 5, 6, 7);
            #pragma unroll
            for (int mt = 0; mt < 4; mt++)
                acc_t[mt] = __builtin_amdgcn_mfma_scale_f32_16x16x128_f8f6f4(
                    a_all[mt][ks], b, acc_t[mt], 0, 0, 0, 0x7f7f7f7f, 0, 0x7f7f7f7f);
        }
        #pragma unroll
        for (int mt = 0; mt < 4; mt++)
            #pragma unroll
            for (int r = 0; r < 4; r++) {
                float v = acc_t[mt][r] * (1.0f / 512.0f);
                ss[mt * 4 + r] += v * v;
            }
        __syncthreads();
    }

    // reduce: over the 16 n-lanes, then cross-wave via LDS, then direct global write
    #pragma unroll
    for (int i = 0; i < 16; i++) {
        #pragma unroll
        for (int off = 1; off < 16; off <<= 1) ss[i] += __shfl_xor(ss[i], off, 64);
    }
    if (mrow == 0) {
        #pragma unroll
        for (int mt = 0; mt < 4; mt++)
            #pragma unroll
            for (int r = 0; r < 4; r++)
                rnred[wave * 64 + mt * 16 + g * 4 + r] = ss[mt * 4 + r];
    }
    __syncthreads();
    if (id < 64)
        rn[row0 + id] = rnred[id] + rnred[64 + id] + rnred[128 + id] + rnred[192 + id];
}

extern "C" void kernel_launch(void* const* d_in, const int* in_sizes, int n_in,
                              void* d_out, int out_size, void* d_ws, size_t ws_size,
                              hipStream_t stream) {
    const float* x        = (const float*)d_in[0];   // [16384,1024]
    const float* concepts = (const float*)d_in[1];   // [512,1024]
    const float* Wq       = (const float*)d_in[2];   // [1024,1024]
    const float* Wk       = (const float*)d_in[3];   // [1024,1024]
    const float* fc_w     = (const float*)d_in[4];   // [1000,1024]
    const float* fc_b     = (const float*)d_in[5];   // [1000]

    const int B = 16384, D = 1024, C = 512, N = 1000;

    float* out  = (float*)d_out;                       // [B,N]
    float* attn = out + (size_t)B * N;                 // [B,C]
    float* sim  = attn + (size_t)B * C;                // [C,C]

    // ---- ws layout (~34.6 MiB) ----
    uint8_t* w = (uint8_t*)d_ws;
    uint8_t* x_f8    = w;                                        // [B,D]     16 MiB
    uint8_t* attn_f8 = w + (16ull << 20);                        // [B,C]      8 MiB
    ushort*  Wq_bf   = (ushort*)(w + (24ull << 20));             // [D,D]      2 MiB
    ushort*  Wk_bf   = (ushort*)(w + (26ull << 20));             // [D,D]      2 MiB
    ushort*  fcw_bf  = (ushort*)(w + (28ull << 20));             // [N,D]      2 MiB
    ushort*  c_bf    = (ushort*)(w + (30ull << 20));             // [C,D]      1 MiB
    ushort*  P2_bf   = (ushort*)(w + (31ull << 20));             // [D,D]      2 MiB
    uint8_t* cT_f8   = w + (33ull << 20);                        // [D,C]    0.5 MiB
    uint8_t* W2T_f8  = w + (33ull << 20) + (512ull << 10);       // [C,D]    0.5 MiB
    uint8_t* W3T_f8  = w + (34ull << 20);                        // [1024,C] 0.5 MiB (tail rows zeroed)
    float*   rn      = (float*)(w + (34ull << 20) + (512ull << 10)); // [B] 64 KiB

    // Reassociation: scores = x @ W2T^T where W2T = c @ (Wq Wk^T)^T  (P2 = Wq @ Wk^T)
    //                out    = (attn @ W3T^T) * rsqrt(|attn@c|^2) + b (W3T = fcw @ c^T)
    // scales: x*1, W2T*16 -> scores scale (1/32)/16 = 1/512 (f32)
    //         attn*32, cT*16 -> rn = |acc/512|^2 (in-kernel, direct write)
    //         attn*32, W3T*16 -> out scale 1/512, * rsqrt(rn), + bias

    prep_all<<<19961, 256, 0, stream>>>(x, Wq, Wk, fc_w, concepts,
                                        x_f8, Wq_bf, Wk_bf, fcw_bf, c_bf, cT_f8, W3T_f8);
    gemm_p2<<<dim3(16, 16), 256, 0, stream>>>(Wq_bf, Wk_bf, P2_bf);
    gemm_batch3<<<320, 256, 0, stream>>>(c_bf, fcw_bf, P2_bf, sim, W3T_f8, W2T_f8);
    // fused scores + sparsemax + rn
    scores_sm_rn<<<B / 64, 256, 0, stream>>>(x_f8, W2T_f8, cT_f8, attn, attn_f8, rn);
    // out = (attn @ W3) * rsqrt(rn) + fc_b   [R4-proven path]
    gemm_f8<float, true, false, true, true><<<dim3((N + 127) / 128, B / 128), 256, 0, stream>>>(
        attn_f8, W3T_f8, fc_b, rn, out, B, N, C, N, 1.0f / 512.0f);
}